// Round 5
// baseline (437.781 us; speedup 1.0000x reference)
//
#include <hip/hip_runtime.h>
#include <hip/hip_bf16.h>
#include <stdint.h>

#define NTOK 49
#define DIM  128
#define NH   4
#define QKVN 384
#define SCALE 0.17677669529663687f
#define WPB 4   // windows per block

typedef __bf16 bfloat_t;
typedef bfloat_t bf16x8 __attribute__((ext_vector_type(8)));
typedef bfloat_t bf16x4 __attribute__((ext_vector_type(4)));
typedef short    s16x4  __attribute__((ext_vector_type(4)));
typedef float    f32x4  __attribute__((ext_vector_type(4)));

#define MFMA32(a, b, c) __builtin_amdgcn_mfma_f32_16x16x32_bf16(a, b, c, 0, 0, 0)
#define MFMA16(a, b, c) __builtin_amdgcn_mfma_f32_16x16x16bf16_1k(a, b, c, 0, 0, 0)

static __device__ __forceinline__ bf16x4 pk4(f32x4 a) {
    bf16x4 r = { (bfloat_t)a[0], (bfloat_t)a[1], (bfloat_t)a[2], (bfloat_t)a[3] };
    return r;
}
static __device__ __forceinline__ s16x4 asi(bf16x4 v) {
    return __builtin_bit_cast(s16x4, v);
}

__global__ void prep_weights(const float* __restrict__ qkvw,
                             const float* __restrict__ projw,
                             bfloat_t* __restrict__ qkvw_b,
                             bfloat_t* __restrict__ projw_b) {
    int i = blockIdx.x * 256 + threadIdx.x;
    if (i < QKVN * DIM) qkvw_b[i] = (bfloat_t)qkvw[i];
    if (i < DIM * DIM)  projw_b[i] = (bfloat_t)projw[i];
}

// cmb[w][h][tok_q(64)][tok_k(64)] = bias + mask; tok_k>=49 -> -1e30; tok_q>=49 -> 0
__global__ void prep_cmb(const float* __restrict__ mask,
                         const float* __restrict__ bias_table,
                         const int* __restrict__ rel_index,
                         float* __restrict__ cmb) {
    int wh = blockIdx.x;            // w*NH + h
    int w = wh >> 2, h = wh & 3;
    for (int idx = threadIdx.x; idx < 4096; idx += 256) {
        int row = idx >> 6, col = idx & 63;   // row=tok_q, col=tok_k
        float v;
        if (col >= NTOK)      v = -1e30f;
        else if (row >= NTOK) v = 0.f;
        else v = bias_table[rel_index[row * NTOK + col] * NH + h]
               + mask[(w * NTOK + row) * NTOK + col];
        cmb[(size_t)wh * 4096 + idx] = v;
    }
}

// Block = WPB windows processed in a 2-barrier pipelined loop; wave = head.
// q,k,v,P register-chained via 16x16x16 MFMA (C/D layout == A/B layout).
// LDS: two 16KB x-buffers (swizzled); ao exchange overlays buf[cur].
__global__ __launch_bounds__(256, 4)
void win_attn(const float* __restrict__ x,
              const float* __restrict__ qkv_b,
              const float* __restrict__ proj_b,
              const bfloat_t* __restrict__ qkvw,
              const bfloat_t* __restrict__ projw,
              const float* __restrict__ cmb,
              float* __restrict__ out, int nw, int Btot) {
    __shared__ __align__(16) char smem[32768];
    const int tid  = threadIdx.x;
    const int wave = tid >> 6;
    const int lane = tid & 63;
    const int g = lane >> 4;
    const int c = lane & 15;
    const int h = wave;
    const int wbase = blockIdx.x * WPB;

    const int srow  = tid >> 5;            // staging: row this thread covers
    const int scol4 = (tid & 31) * 4;      // 4-float column group
    const int sbyte = srow * 256 + ((scol4 * 2) ^ ((srow & 7) << 4));

    // ---- prologue: stage x[wbase] -> buf0 ----
    {
        const float* xb = x + (size_t)wbase * (NTOK * DIM);
        #pragma unroll
        for (int i = 0; i < 8; ++i) {
            const int s = tid + i * 256;
            const int row = s >> 5, col4 = (s & 31) * 4;
            f32x4 v = (row < NTOK) ? *(const f32x4*)(xb + row * DIM + col4)
                                   : (f32x4){0.f, 0.f, 0.f, 0.f};
            *(bf16x4*)(smem + row * 256 + ((col4 * 2) ^ ((row & 7) << 4))) = pk4(v);
        }
    }
    __syncthreads();

    int cur = 0;
    for (int w = 0; w < WPB; ++w) {
        const int b = wbase + w;
        char* bufc = smem + cur * 16384;
        char* bufn = smem + (cur ^ 1) * 16384;

        // ---- 1. issue next window's x loads (consumed in phase 4a) ----
        const bool have_next = (w + 1 < WPB) && (b + 1 < Btot);
        f32x4 pre[8];
        if (have_next) {
            const float* xb = x + (size_t)(b + 1) * (NTOK * DIM);
            #pragma unroll
            for (int i = 0; i < 8; ++i) {
                const int s = tid + i * 256;
                const int row = s >> 5, col4 = (s & 31) * 4;
                pre[i] = (row < NTOK) ? *(const f32x4*)(xb + row * DIM + col4)
                                      : (f32x4){0.f, 0.f, 0.f, 0.f};
            }
        }

        // x A-frag (K=32): [tok=t*16+c][d = ks*32 + g*8 .. +7]
        #define LDX(t, ks) (*(const bf16x8*)(bufc + ((t)*16 + c) * 256 + \
                            (((ks)*64 + g*16) ^ ((c & 7) << 4))))

        bf16x4 qp[2][4], kp[2][4], vp[4][2];

        // ---- 2. QKV GEMMs from buf[cur] ----
        {
            f32x4 acc[2][4];
            #pragma unroll
            for (int mtd = 0; mtd < 2; ++mtd) {
                const f32x4 qb4 = *(const f32x4*)(qkv_b + h * 32 + mtd * 16 + g * 4);
                #pragma unroll
                for (int nt = 0; nt < 4; ++nt) acc[mtd][nt] = qb4;
            }
            #pragma unroll
            for (int ks = 0; ks < 4; ++ks) {
                bf16x8 w0 = *(const bf16x8*)(qkvw + (h * 32 +  0 + c) * DIM + ks * 32 + g * 8);
                bf16x8 w1 = *(const bf16x8*)(qkvw + (h * 32 + 16 + c) * DIM + ks * 32 + g * 8);
                #pragma unroll
                for (int nt = 0; nt < 4; ++nt) {
                    bf16x8 a = LDX(nt, ks);
                    acc[0][nt] = MFMA32(w0, a, acc[0][nt]);
                    acc[1][nt] = MFMA32(w1, a, acc[1][nt]);
                }
            }
            #pragma unroll
            for (int ds = 0; ds < 2; ++ds)
                #pragma unroll
                for (int nt = 0; nt < 4; ++nt) {
                    f32x4 a = acc[ds][nt];
                    f32x4 sc = { a[0]*SCALE, a[1]*SCALE, a[2]*SCALE, a[3]*SCALE };
                    qp[ds][nt] = pk4(sc);
                }
        }
        {
            f32x4 acc[2][4];
            #pragma unroll
            for (int mtd = 0; mtd < 2; ++mtd) {
                const f32x4 kb4 = *(const f32x4*)(qkv_b + DIM + h * 32 + mtd * 16 + g * 4);
                #pragma unroll
                for (int nt = 0; nt < 4; ++nt) acc[mtd][nt] = kb4;
            }
            #pragma unroll
            for (int ks = 0; ks < 4; ++ks) {
                bf16x8 w0 = *(const bf16x8*)(qkvw + (DIM + h * 32 +  0 + c) * DIM + ks * 32 + g * 8);
                bf16x8 w1 = *(const bf16x8*)(qkvw + (DIM + h * 32 + 16 + c) * DIM + ks * 32 + g * 8);
                #pragma unroll
                for (int nt = 0; nt < 4; ++nt) {
                    bf16x8 a = LDX(nt, ks);
                    acc[0][nt] = MFMA32(w0, a, acc[0][nt]);
                    acc[1][nt] = MFMA32(w1, a, acc[1][nt]);
                }
            }
            #pragma unroll
            for (int ds = 0; ds < 2; ++ds)
                #pragma unroll
                for (int nt = 0; nt < 4; ++nt) kp[ds][nt] = pk4(acc[ds][nt]);
        }
        {
            f32x4 acc[4][2];
            #pragma unroll
            for (int nt = 0; nt < 2; ++nt) {
                const float vb = qkv_b[2 * DIM + h * 32 + nt * 16 + c];
                #pragma unroll
                for (int mt = 0; mt < 4; ++mt) acc[mt][nt] = (f32x4){vb, vb, vb, vb};
            }
            #pragma unroll
            for (int ks = 0; ks < 4; ++ks) {
                bf16x8 w0 = *(const bf16x8*)(qkvw + (2 * DIM + h * 32 +  0 + c) * DIM + ks * 32 + g * 8);
                bf16x8 w1 = *(const bf16x8*)(qkvw + (2 * DIM + h * 32 + 16 + c) * DIM + ks * 32 + g * 8);
                #pragma unroll
                for (int mt = 0; mt < 4; ++mt) {
                    bf16x8 a = LDX(mt, ks);
                    acc[mt][0] = MFMA32(a, w0, acc[mt][0]);
                    acc[mt][1] = MFMA32(a, w1, acc[mt][1]);
                }
            }
            #pragma unroll
            for (int mt = 0; mt < 4; ++mt)
                #pragma unroll
                for (int nt = 0; nt < 2; ++nt) vp[mt][nt] = pk4(acc[mt][nt]);
        }
        #undef LDX

        // ---- 3. barrier: QKV reads of buf[cur] complete ----
        __syncthreads();

        // ---- 4a. write prefetched x -> buf[nxt] ----
        if (have_next) {
            #pragma unroll
            for (int i = 0; i < 8; ++i) {
                const int s = tid + i * 256;
                const int row = s >> 5, col4 = (s & 31) * 4;
                *(bf16x4*)(bufn + row * 256 + ((col4 * 2) ^ ((row & 7) << 4))) = pk4(pre[i]);
            }
        }

        // ---- 4b. S^T = k.q^T + cmb^T, softmax, then O^T = vT.P^T (all regs) ----
        bf16x4 pp[4][4];
        float dinv[4];
        {
            const float* cw = cmb + (size_t)((b % nw) * NH + h) * 4096;
            #pragma unroll
            for (int ntq = 0; ntq < 4; ++ntq) {
                f32x4 s[4];
                #pragma unroll
                for (int mtk = 0; mtk < 4; ++mtk)
                    s[mtk] = *(const f32x4*)(cw + (ntq * 16 + c) * 64 + mtk * 16 + g * 4);
                #pragma unroll
                for (int mtk = 0; mtk < 4; ++mtk) {
                    s[mtk] = MFMA16(asi(kp[0][mtk]), asi(qp[0][ntq]), s[mtk]);
                    s[mtk] = MFMA16(asi(kp[1][mtk]), asi(qp[1][ntq]), s[mtk]);
                }
                float m = s[0][0];
                #pragma unroll
                for (int mtk = 0; mtk < 4; ++mtk)
                    #pragma unroll
                    for (int r = 0; r < 4; ++r) m = fmaxf(m, s[mtk][r]);
                m = fmaxf(m, __shfl_xor(m, 16));
                m = fmaxf(m, __shfl_xor(m, 32));
                float sum = 0.f;
                #pragma unroll
                for (int mtk = 0; mtk < 4; ++mtk)
                    #pragma unroll
                    for (int r = 0; r < 4; ++r) {
                        float p = __expf(s[mtk][r] - m);
                        s[mtk][r] = p;
                        sum += p;
                    }
                sum += __shfl_xor(sum, 16);
                sum += __shfl_xor(sum, 32);
                dinv[ntq] = 1.f / sum;
                #pragma unroll
                for (int mtk = 0; mtk < 4; ++mtk) pp[mtk][ntq] = pk4(s[mtk]);
            }
        }
        {
            f32x4 o[2][4];
            #pragma unroll
            for (int mtd = 0; mtd < 2; ++mtd)
                #pragma unroll
                for (int ntq = 0; ntq < 4; ++ntq) o[mtd][ntq] = (f32x4){0.f, 0.f, 0.f, 0.f};
            #pragma unroll
            for (int mtk = 0; mtk < 4; ++mtk)
                #pragma unroll
                for (int mtd = 0; mtd < 2; ++mtd)
                    #pragma unroll
                    for (int ntq = 0; ntq < 4; ++ntq)
                        o[mtd][ntq] = MFMA16(asi(vp[mtk][mtd]), asi(pp[mtk][ntq]), o[mtd][ntq]);
            // ao[tok][d] bf16 overlays buf[cur]
            #pragma unroll
            for (int mtd = 0; mtd < 2; ++mtd)
                #pragma unroll
                for (int ntq = 0; ntq < 4; ++ntq) {
                    f32x4 a = o[mtd][ntq];
                    f32x4 sc = { a[0]*dinv[ntq], a[1]*dinv[ntq], a[2]*dinv[ntq], a[3]*dinv[ntq] };
                    const int byte = (ntq*16 + c)*256 + ((((h*4 + 2*mtd + (g>>1)) ^ c) & 15) << 4) + ((g&1) << 3);
                    *(bf16x4*)(bufc + byte) = pk4(sc);
                }
        }

        // ---- 5. barrier: ao + next-x writes complete ----
        __syncthreads();

        // ---- 6. proj from ao(buf[cur]); fp32 stores ----
        {
            f32x4 po[2][4];
            #pragma unroll
            for (int mtO = 0; mtO < 2; ++mtO) {
                const f32x4 pb4 = *(const f32x4*)(proj_b + wave * 32 + mtO * 16 + g * 4);
                #pragma unroll
                for (int nt = 0; nt < 4; ++nt) po[mtO][nt] = pb4;
            }
            #pragma unroll
            for (int ks = 0; ks < 4; ++ks) {
                bf16x8 w0 = *(const bf16x8*)(projw + (wave * 32 +  0 + c) * DIM + ks * 32 + g * 8);
                bf16x8 w1 = *(const bf16x8*)(projw + (wave * 32 + 16 + c) * DIM + ks * 32 + g * 8);
                bf16x8 aof[4];
                #pragma unroll
                for (int nt = 0; nt < 4; ++nt)
                    aof[nt] = *(const bf16x8*)(bufc + (nt*16 + c)*256 + ((((ks*4 + g) ^ c) & 15) << 4));
                #pragma unroll
                for (int nt = 0; nt < 4; ++nt) {
                    po[0][nt] = MFMA32(w0, aof[nt], po[0][nt]);
                    po[1][nt] = MFMA32(w1, aof[nt], po[1][nt]);
                }
            }
            float* og = out + (size_t)b * (NTOK * DIM);
            #pragma unroll
            for (int nt = 0; nt < 4; ++nt) {
                const int tok = nt * 16 + c;
                if (tok < NTOK) {
                    #pragma unroll
                    for (int mtO = 0; mtO < 2; ++mtO)
                        *(f32x4*)(og + tok * DIM + wave * 32 + mtO * 16 + g * 4) = po[mtO][nt];
                }
            }
        }
        cur ^= 1;
    }
}

extern "C" void kernel_launch(void* const* d_in, const int* in_sizes, int n_in,
                              void* d_out, int out_size, void* d_ws, size_t ws_size,
                              hipStream_t stream) {
    (void)n_in; (void)out_size; (void)ws_size;
    const float* x          = (const float*)d_in[0];
    const float* mask       = (const float*)d_in[1];
    const float* qkv_w      = (const float*)d_in[2];
    const float* qkv_b      = (const float*)d_in[3];
    const float* proj_w     = (const float*)d_in[4];
    const float* proj_b     = (const float*)d_in[5];
    const float* bias_table = (const float*)d_in[6];
    const int*   rel_index  = (const int*)d_in[7];
    float* out = (float*)d_out;

    char* ws = (char*)d_ws;
    bfloat_t* qkvw_b  = (bfloat_t*)ws;              // 98304 B
    bfloat_t* projw_b = (bfloat_t*)(ws + 98304);    // 32768 B
    float*    cmb     = (float*)(ws + 131072);      // nw*NH*64*64*4 B

    const int B  = in_sizes[0] / (NTOK * DIM);
    const int nw = in_sizes[1] / (NTOK * NTOK);

    prep_weights<<<dim3((QKVN * DIM + 255) / 256), dim3(256), 0, stream>>>(qkv_w, proj_w, qkvw_b, projw_b);
    prep_cmb<<<dim3(nw * NH), dim3(256), 0, stream>>>(mask, bias_table, rel_index, cmb);
    win_attn<<<dim3((B + WPB - 1) / WPB), dim3(256), 0, stream>>>(x, qkv_b, proj_b, qkvw_b, projw_b, cmb, out, nw, B);
}

// Round 6
// 365.959 us; speedup vs baseline: 1.1963x; 1.1963x over previous
//
#include <hip/hip_runtime.h>
#include <hip/hip_bf16.h>
#include <stdint.h>

#define NTOK 49
#define DIM  128
#define NH   4
#define QKVN 384
#define SCALE 0.17677669529663687f

typedef __bf16 bfloat_t;
typedef bfloat_t bf16x8 __attribute__((ext_vector_type(8)));
typedef bfloat_t bf16x4 __attribute__((ext_vector_type(4)));
typedef short    s16x4  __attribute__((ext_vector_type(4)));
typedef float    f32x4  __attribute__((ext_vector_type(4)));

#define MFMA32(a, b, c) __builtin_amdgcn_mfma_f32_16x16x32_bf16(a, b, c, 0, 0, 0)
#define MFMA16(a, b, c) __builtin_amdgcn_mfma_f32_16x16x16bf16_1k(a, b, c, 0, 0, 0)

static __device__ __forceinline__ bf16x4 pk4(f32x4 a) {
    bf16x4 r = { (bfloat_t)a[0], (bfloat_t)a[1], (bfloat_t)a[2], (bfloat_t)a[3] };
    return r;
}
static __device__ __forceinline__ s16x4 asi(bf16x4 v) {
    return __builtin_bit_cast(s16x4, v);
}

__global__ void prep_weights(const float* __restrict__ qkvw,
                             const float* __restrict__ projw,
                             bfloat_t* __restrict__ qkvw_b,
                             bfloat_t* __restrict__ projw_b) {
    int i = blockIdx.x * 256 + threadIdx.x;
    if (i < QKVN * DIM) qkvw_b[i] = (bfloat_t)qkvw[i];
    if (i < DIM * DIM)  projw_b[i] = (bfloat_t)projw[i];
}

// cmb[w][h][tok_q(64)][tok_k(64)] = bias + mask; tok_k>=49 -> -1e30; tok_q>=49 -> 0
__global__ void prep_cmb(const float* __restrict__ mask,
                         const float* __restrict__ bias_table,
                         const int* __restrict__ rel_index,
                         float* __restrict__ cmb) {
    int wh = blockIdx.x;            // w*NH + h
    int w = wh >> 2, h = wh & 3;
    for (int idx = threadIdx.x; idx < 4096; idx += 256) {
        int row = idx >> 6, col = idx & 63;   // row=tok_q, col=tok_k
        float v;
        if (col >= NTOK)      v = -1e30f;
        else if (row >= NTOK) v = 0.f;
        else v = bias_table[rel_index[row * NTOK + col] * NH + h]
               + mask[(w * NTOK + row) * NTOK + col];
        cmb[(size_t)wh * 4096 + idx] = v;
    }
}

// One block = one window; wave = head. All per-head tensors (q,k,v,P) live in
// registers: 16x16x16 MFMA operand layout == 16x16 C/D layout, so packed accs
// chain directly into the next MFMA. LDS: x tile 16KB (swizzled), overlaid by
// the 16KB ao exchange for proj. 3 barriers.
// launch_bounds(256,8): 8 blocks/CU = 32 waves/CU (HW max). VGPR must stay <=64.
__global__ __launch_bounds__(256, 8)
void win_attn(const float* __restrict__ x,
              const float* __restrict__ qkv_b,
              const float* __restrict__ proj_b,
              const bfloat_t* __restrict__ qkvw,
              const bfloat_t* __restrict__ projw,
              const float* __restrict__ cmb,
              float* __restrict__ out, int nw) {
    __shared__ __align__(16) char smem[16384];
    const int b    = blockIdx.x;
    const int tid  = threadIdx.x;
    const int wave = tid >> 6;
    const int lane = tid & 63;
    const int g = lane >> 4;
    const int c = lane & 15;
    const int h = wave;

    // ---- stage x -> LDS bf16 [64 tok][128 d], 16B-granule XOR swizzle ----
    {
        const float* xb = x + (size_t)b * (NTOK * DIM);
        #pragma unroll
        for (int i = 0; i < 8; ++i) {
            const int s = tid + i * 256;            // 0..2047 b64 slots
            const int row = s >> 5, col4 = (s & 31) * 4;
            f32x4 v = (row < NTOK) ? *(const f32x4*)(xb + row * DIM + col4)
                                   : (f32x4){0.f, 0.f, 0.f, 0.f};
            *(bf16x4*)(smem + row * 256 + ((col4 * 2) ^ ((row & 7) << 4))) = pk4(v);
        }
    }
    __syncthreads();

    // x A-frag (K=32): [tok=t*16+c][d = ks*32 + g*8 .. +7]
    #define LDX(t, ks) (*(const bf16x8*)(smem + ((t)*16 + c) * 256 + \
                        (((ks)*64 + g*16) ^ ((c & 7) << 4))))

    bf16x4 qp[2][4], kp[2][4], vp[4][2];   // packed frags, chunk layout = C/D layout

    // ---- q^T = Wq_h . x^T : D[m=d(2 tiles)][n=tok(4 tiles)] ----
    {
        f32x4 acc[2][4];
        #pragma unroll
        for (int mtd = 0; mtd < 2; ++mtd) {
            const f32x4 qb4 = *(const f32x4*)(qkv_b + h * 32 + mtd * 16 + g * 4);
            #pragma unroll
            for (int nt = 0; nt < 4; ++nt) acc[mtd][nt] = qb4;
        }
        #pragma unroll
        for (int ks = 0; ks < 4; ++ks) {
            bf16x8 w0 = *(const bf16x8*)(qkvw + (h * 32 +  0 + c) * DIM + ks * 32 + g * 8);
            bf16x8 w1 = *(const bf16x8*)(qkvw + (h * 32 + 16 + c) * DIM + ks * 32 + g * 8);
            #pragma unroll
            for (int nt = 0; nt < 4; ++nt) {
                bf16x8 a = LDX(nt, ks);
                acc[0][nt] = MFMA32(w0, a, acc[0][nt]);
                acc[1][nt] = MFMA32(w1, a, acc[1][nt]);
            }
        }
        #pragma unroll
        for (int ds = 0; ds < 2; ++ds)
            #pragma unroll
            for (int nt = 0; nt < 4; ++nt) {
                f32x4 a = acc[ds][nt];
                f32x4 sc = { a[0]*SCALE, a[1]*SCALE, a[2]*SCALE, a[3]*SCALE };
                qp[ds][nt] = pk4(sc);
            }
    }

    // ---- k^T = Wk_h . x^T ----
    {
        f32x4 acc[2][4];
        #pragma unroll
        for (int mtd = 0; mtd < 2; ++mtd) {
            const f32x4 kb4 = *(const f32x4*)(qkv_b + DIM + h * 32 + mtd * 16 + g * 4);
            #pragma unroll
            for (int nt = 0; nt < 4; ++nt) acc[mtd][nt] = kb4;
        }
        #pragma unroll
        for (int ks = 0; ks < 4; ++ks) {
            bf16x8 w0 = *(const bf16x8*)(qkvw + (DIM + h * 32 +  0 + c) * DIM + ks * 32 + g * 8);
            bf16x8 w1 = *(const bf16x8*)(qkvw + (DIM + h * 32 + 16 + c) * DIM + ks * 32 + g * 8);
            #pragma unroll
            for (int nt = 0; nt < 4; ++nt) {
                bf16x8 a = LDX(nt, ks);
                acc[0][nt] = MFMA32(w0, a, acc[0][nt]);
                acc[1][nt] = MFMA32(w1, a, acc[1][nt]);
            }
        }
        #pragma unroll
        for (int ds = 0; ds < 2; ++ds)
            #pragma unroll
            for (int nt = 0; nt < 4; ++nt) kp[ds][nt] = pk4(acc[ds][nt]);
    }

    // ---- v = x . Wv_h^T : D[m=tok(4 tiles)][n=d(2 tiles)] ----
    {
        f32x4 acc[4][2];
        #pragma unroll
        for (int nt = 0; nt < 2; ++nt) {
            const float vb = qkv_b[2 * DIM + h * 32 + nt * 16 + c];
            #pragma unroll
            for (int mt = 0; mt < 4; ++mt) acc[mt][nt] = (f32x4){vb, vb, vb, vb};
        }
        #pragma unroll
        for (int ks = 0; ks < 4; ++ks) {
            bf16x8 w0 = *(const bf16x8*)(qkvw + (2 * DIM + h * 32 +  0 + c) * DIM + ks * 32 + g * 8);
            bf16x8 w1 = *(const bf16x8*)(qkvw + (2 * DIM + h * 32 + 16 + c) * DIM + ks * 32 + g * 8);
            #pragma unroll
            for (int mt = 0; mt < 4; ++mt) {
                bf16x8 a = LDX(mt, ks);
                acc[mt][0] = MFMA32(a, w0, acc[mt][0]);
                acc[mt][1] = MFMA32(a, w1, acc[mt][1]);
            }
        }
        #pragma unroll
        for (int mt = 0; mt < 4; ++mt)
            #pragma unroll
            for (int nt = 0; nt < 2; ++nt) vp[mt][nt] = pk4(acc[mt][nt]);
    }

    // ---- S^T = k . q^T (K=16 MFMA, operands straight from qp/kp), softmax ----
    bf16x4 pp[4][4];         // packed P frags [mtk][ntq]
    float dinv[4];
    {
        const float* cw = cmb + (size_t)((b % nw) * NH + h) * 4096;
        #pragma unroll
        for (int ntq = 0; ntq < 4; ++ntq) {
            f32x4 s[4];
            #pragma unroll
            for (int mtk = 0; mtk < 4; ++mtk)
                s[mtk] = *(const f32x4*)(cw + (ntq * 16 + c) * 64 + mtk * 16 + g * 4);
            #pragma unroll
            for (int mtk = 0; mtk < 4; ++mtk) {
                s[mtk] = MFMA16(asi(kp[0][mtk]), asi(qp[0][ntq]), s[mtk]);
                s[mtk] = MFMA16(asi(kp[1][mtk]), asi(qp[1][ntq]), s[mtk]);
            }
            float m = s[0][0];
            #pragma unroll
            for (int mtk = 0; mtk < 4; ++mtk)
                #pragma unroll
                for (int r = 0; r < 4; ++r) m = fmaxf(m, s[mtk][r]);
            m = fmaxf(m, __shfl_xor(m, 16));
            m = fmaxf(m, __shfl_xor(m, 32));
            float sum = 0.f;
            #pragma unroll
            for (int mtk = 0; mtk < 4; ++mtk)
                #pragma unroll
                for (int r = 0; r < 4; ++r) {
                    float p = __expf(s[mtk][r] - m);
                    s[mtk][r] = p;
                    sum += p;
                }
            sum += __shfl_xor(sum, 16);
            sum += __shfl_xor(sum, 32);
            dinv[ntq] = 1.f / sum;
            #pragma unroll
            for (int mtk = 0; mtk < 4; ++mtk) pp[mtk][ntq] = pk4(s[mtk]);
        }
    }

    // ---- O^T = vT . P^T (K=16 MFMA, operands straight from vp/pp) ----
    f32x4 o[2][4];
    {
        #pragma unroll
        for (int mtd = 0; mtd < 2; ++mtd)
            #pragma unroll
            for (int ntq = 0; ntq < 4; ++ntq) o[mtd][ntq] = (f32x4){0.f, 0.f, 0.f, 0.f};
        #pragma unroll
        for (int mtk = 0; mtk < 4; ++mtk)
            #pragma unroll
            for (int mtd = 0; mtd < 2; ++mtd)
                #pragma unroll
                for (int ntq = 0; ntq < 4; ++ntq)
                    o[mtd][ntq] = MFMA16(asi(vp[mtk][mtd]), asi(pp[mtk][ntq]), o[mtd][ntq]);
        #pragma unroll
        for (int mtd = 0; mtd < 2; ++mtd)
            #pragma unroll
            for (int ntq = 0; ntq < 4; ++ntq)
                #pragma unroll
                for (int r = 0; r < 4; ++r) o[mtd][ntq][r] *= dinv[ntq];
    }

    __syncthreads();   // all waves done with x region; reuse as ao exchange
    // ao[tok][d] bf16, 16B-granule swizzle ^ (c&15)
    #pragma unroll
    for (int mtd = 0; mtd < 2; ++mtd)
        #pragma unroll
        for (int ntq = 0; ntq < 4; ++ntq) {
            const int byte = (ntq*16 + c)*256 + ((((h*4 + 2*mtd + (g>>1)) ^ c) & 15) << 4) + ((g&1) << 3);
            *(bf16x4*)(smem + byte) = pk4(o[mtd][ntq]);
        }
    __syncthreads();

    // ---- out^T = Wp . ao^T : wave owns 32 output cols; f32x4 stores ----
    {
        f32x4 po[2][4];
        #pragma unroll
        for (int mtO = 0; mtO < 2; ++mtO) {
            const f32x4 pb4 = *(const f32x4*)(proj_b + wave * 32 + mtO * 16 + g * 4);
            #pragma unroll
            for (int nt = 0; nt < 4; ++nt) po[mtO][nt] = pb4;
        }
        #pragma unroll
        for (int ks = 0; ks < 4; ++ks) {
            bf16x8 w0 = *(const bf16x8*)(projw + (wave * 32 +  0 + c) * DIM + ks * 32 + g * 8);
            bf16x8 w1 = *(const bf16x8*)(projw + (wave * 32 + 16 + c) * DIM + ks * 32 + g * 8);
            bf16x8 aof[4];
            #pragma unroll
            for (int nt = 0; nt < 4; ++nt)
                aof[nt] = *(const bf16x8*)(smem + (nt*16 + c)*256 + ((((ks*4 + g) ^ c) & 15) << 4));
            #pragma unroll
            for (int nt = 0; nt < 4; ++nt) {
                po[0][nt] = MFMA32(w0, aof[nt], po[0][nt]);
                po[1][nt] = MFMA32(w1, aof[nt], po[1][nt]);
            }
        }
        float* og = out + (size_t)b * (NTOK * DIM);
        #pragma unroll
        for (int nt = 0; nt < 4; ++nt) {
            const int tok = nt * 16 + c;
            if (tok < NTOK) {
                #pragma unroll
                for (int mtO = 0; mtO < 2; ++mtO)
                    *(f32x4*)(og + tok * DIM + wave * 32 + mtO * 16 + g * 4) = po[mtO][nt];
            }
        }
    }
    #undef LDX
}

extern "C" void kernel_launch(void* const* d_in, const int* in_sizes, int n_in,
                              void* d_out, int out_size, void* d_ws, size_t ws_size,
                              hipStream_t stream) {
    (void)n_in; (void)out_size; (void)ws_size;
    const float* x          = (const float*)d_in[0];
    const float* mask       = (const float*)d_in[1];
    const float* qkv_w      = (const float*)d_in[2];
    const float* qkv_b      = (const float*)d_in[3];
    const float* proj_w     = (const float*)d_in[4];
    const float* proj_b     = (const float*)d_in[5];
    const float* bias_table = (const float*)d_in[6];
    const int*   rel_index  = (const int*)d_in[7];
    float* out = (float*)d_out;

    char* ws = (char*)d_ws;
    bfloat_t* qkvw_b  = (bfloat_t*)ws;              // 98304 B
    bfloat_t* projw_b = (bfloat_t*)(ws + 98304);    // 32768 B
    float*    cmb     = (float*)(ws + 131072);      // nw*NH*64*64*4 B

    const int B  = in_sizes[0] / (NTOK * DIM);
    const int nw = in_sizes[1] / (NTOK * NTOK);

    prep_weights<<<dim3((QKVN * DIM + 255) / 256), dim3(256), 0, stream>>>(qkv_w, proj_w, qkvw_b, projw_b);
    prep_cmb<<<dim3(nw * NH), dim3(256), 0, stream>>>(mask, bias_table, rel_index, cmb);
    win_attn<<<dim3(B), dim3(256), 0, stream>>>(x, qkv_b, proj_b, qkvw_b, projw_b, cmb, out, nw);
}

// Round 7
// 309.584 us; speedup vs baseline: 1.4141x; 1.1821x over previous
//
#include <hip/hip_runtime.h>
#include <hip/hip_bf16.h>
#include <stdint.h>

#define NTOK 49
#define DIM  128
#define NH   4
#define QKVN 384
#define SCALE 0.17677669529663687f

typedef __bf16 bfloat_t;
typedef bfloat_t bf16x8 __attribute__((ext_vector_type(8)));
typedef bfloat_t bf16x4 __attribute__((ext_vector_type(4)));
typedef short    s16x4  __attribute__((ext_vector_type(4)));
typedef float    f32x4  __attribute__((ext_vector_type(4)));

#define MFMA32(a, b, c) __builtin_amdgcn_mfma_f32_16x16x32_bf16(a, b, c, 0, 0, 0)
#define MFMA16(a, b, c) __builtin_amdgcn_mfma_f32_16x16x16bf16_1k(a, b, c, 0, 0, 0)

static __device__ __forceinline__ bf16x4 pk4(f32x4 a) {
    bf16x4 r = { (bfloat_t)a[0], (bfloat_t)a[1], (bfloat_t)a[2], (bfloat_t)a[3] };
    return r;
}
static __device__ __forceinline__ s16x4 asi(bf16x4 v) {
    return __builtin_bit_cast(s16x4, v);
}

__global__ void prep_weights(const float* __restrict__ qkvw,
                             const float* __restrict__ projw,
                             bfloat_t* __restrict__ qkvw_b,
                             bfloat_t* __restrict__ projw_b) {
    int i = blockIdx.x * 256 + threadIdx.x;
    if (i < QKVN * DIM) qkvw_b[i] = (bfloat_t)qkvw[i];
    if (i < DIM * DIM)  projw_b[i] = (bfloat_t)projw[i];
}

// cmb[w][h][tok_q(64)][tok_k(64)] = bias + mask; tok_k>=49 -> -1e30; tok_q>=49 -> 0
__global__ void prep_cmb(const float* __restrict__ mask,
                         const float* __restrict__ bias_table,
                         const int* __restrict__ rel_index,
                         float* __restrict__ cmb) {
    int wh = blockIdx.x;            // w*NH + h
    int w = wh >> 2, h = wh & 3;
    for (int idx = threadIdx.x; idx < 4096; idx += 256) {
        int row = idx >> 6, col = idx & 63;   // row=tok_q, col=tok_k
        float v;
        if (col >= NTOK)      v = -1e30f;
        else if (row >= NTOK) v = 0.f;
        else v = bias_table[rel_index[row * NTOK + col] * NH + h]
               + mask[(w * NTOK + row) * NTOK + col];
        cmb[(size_t)wh * 4096 + idx] = v;
    }
}

// One block = one window; wave = head. All per-head tensors (q,k,v,P) live in
// registers: 16x16x16 MFMA operand layout == 16x16 C/D layout, so packed accs
// chain directly into the next MFMA. LDS: x tile 16KB (swizzled), overlaid by
// the 16KB ao exchange for proj. 3 barriers.
// launch_bounds(256,6): 6 blocks/CU, VGPR budget 84 >= the 64 the body needs
// (bound 8 -> budget 64 < live set -> catastrophic spill, R6: FETCH 534MB).
__global__ __launch_bounds__(256, 6)
void win_attn(const float* __restrict__ x,
              const float* __restrict__ qkv_b,
              const float* __restrict__ proj_b,
              const bfloat_t* __restrict__ qkvw,
              const bfloat_t* __restrict__ projw,
              const float* __restrict__ cmb,
              float* __restrict__ out, int nw) {
    __shared__ __align__(16) char smem[16384];
    const int b    = blockIdx.x;
    const int tid  = threadIdx.x;
    const int wave = tid >> 6;
    const int lane = tid & 63;
    const int g = lane >> 4;
    const int c = lane & 15;
    const int h = wave;

    // ---- stage x -> LDS bf16 [64 tok][128 d], 16B-granule XOR swizzle ----
    {
        const float* xb = x + (size_t)b * (NTOK * DIM);
        #pragma unroll
        for (int i = 0; i < 8; ++i) {
            const int s = tid + i * 256;            // 0..2047 b64 slots
            const int row = s >> 5, col4 = (s & 31) * 4;
            f32x4 v = (row < NTOK) ? *(const f32x4*)(xb + row * DIM + col4)
                                   : (f32x4){0.f, 0.f, 0.f, 0.f};
            *(bf16x4*)(smem + row * 256 + ((col4 * 2) ^ ((row & 7) << 4))) = pk4(v);
        }
    }
    __syncthreads();

    // x A-frag (K=32): [tok=t*16+c][d = ks*32 + g*8 .. +7]
    #define LDX(t, ks) (*(const bf16x8*)(smem + ((t)*16 + c) * 256 + \
                        (((ks)*64 + g*16) ^ ((c & 7) << 4))))

    bf16x4 qp[2][4], kp[2][4], vp[4][2];   // packed frags, chunk layout = C/D layout

    // ---- q^T = Wq_h . x^T : D[m=d(2 tiles)][n=tok(4 tiles)] ----
    {
        f32x4 acc[2][4];
        #pragma unroll
        for (int mtd = 0; mtd < 2; ++mtd) {
            const f32x4 qb4 = *(const f32x4*)(qkv_b + h * 32 + mtd * 16 + g * 4);
            #pragma unroll
            for (int nt = 0; nt < 4; ++nt) acc[mtd][nt] = qb4;
        }
        #pragma unroll
        for (int ks = 0; ks < 4; ++ks) {
            bf16x8 w0 = *(const bf16x8*)(qkvw + (h * 32 +  0 + c) * DIM + ks * 32 + g * 8);
            bf16x8 w1 = *(const bf16x8*)(qkvw + (h * 32 + 16 + c) * DIM + ks * 32 + g * 8);
            #pragma unroll
            for (int nt = 0; nt < 4; ++nt) {
                bf16x8 a = LDX(nt, ks);
                acc[0][nt] = MFMA32(w0, a, acc[0][nt]);
                acc[1][nt] = MFMA32(w1, a, acc[1][nt]);
            }
        }
        #pragma unroll
        for (int ds = 0; ds < 2; ++ds)
            #pragma unroll
            for (int nt = 0; nt < 4; ++nt) {
                f32x4 a = acc[ds][nt];
                f32x4 sc = { a[0]*SCALE, a[1]*SCALE, a[2]*SCALE, a[3]*SCALE };
                qp[ds][nt] = pk4(sc);
            }
    }

    // ---- k^T = Wk_h . x^T ----
    {
        f32x4 acc[2][4];
        #pragma unroll
        for (int mtd = 0; mtd < 2; ++mtd) {
            const f32x4 kb4 = *(const f32x4*)(qkv_b + DIM + h * 32 + mtd * 16 + g * 4);
            #pragma unroll
            for (int nt = 0; nt < 4; ++nt) acc[mtd][nt] = kb4;
        }
        #pragma unroll
        for (int ks = 0; ks < 4; ++ks) {
            bf16x8 w0 = *(const bf16x8*)(qkvw + (DIM + h * 32 +  0 + c) * DIM + ks * 32 + g * 8);
            bf16x8 w1 = *(const bf16x8*)(qkvw + (DIM + h * 32 + 16 + c) * DIM + ks * 32 + g * 8);
            #pragma unroll
            for (int nt = 0; nt < 4; ++nt) {
                bf16x8 a = LDX(nt, ks);
                acc[0][nt] = MFMA32(w0, a, acc[0][nt]);
                acc[1][nt] = MFMA32(w1, a, acc[1][nt]);
            }
        }
        #pragma unroll
        for (int ds = 0; ds < 2; ++ds)
            #pragma unroll
            for (int nt = 0; nt < 4; ++nt) kp[ds][nt] = pk4(acc[ds][nt]);
    }

    // ---- v = x . Wv_h^T : D[m=tok(4 tiles)][n=d(2 tiles)] ----
    {
        f32x4 acc[4][2];
        #pragma unroll
        for (int nt = 0; nt < 2; ++nt) {
            const float vb = qkv_b[2 * DIM + h * 32 + nt * 16 + c];
            #pragma unroll
            for (int mt = 0; mt < 4; ++mt) acc[mt][nt] = (f32x4){vb, vb, vb, vb};
        }
        #pragma unroll
        for (int ks = 0; ks < 4; ++ks) {
            bf16x8 w0 = *(const bf16x8*)(qkvw + (2 * DIM + h * 32 +  0 + c) * DIM + ks * 32 + g * 8);
            bf16x8 w1 = *(const bf16x8*)(qkvw + (2 * DIM + h * 32 + 16 + c) * DIM + ks * 32 + g * 8);
            #pragma unroll
            for (int mt = 0; mt < 4; ++mt) {
                bf16x8 a = LDX(mt, ks);
                acc[mt][0] = MFMA32(a, w0, acc[mt][0]);
                acc[mt][1] = MFMA32(a, w1, acc[mt][1]);
            }
        }
        #pragma unroll
        for (int mt = 0; mt < 4; ++mt)
            #pragma unroll
            for (int nt = 0; nt < 2; ++nt) vp[mt][nt] = pk4(acc[mt][nt]);
    }

    // ---- S^T = k . q^T (K=16 MFMA, operands straight from qp/kp), softmax ----
    bf16x4 pp[4][4];         // packed P frags [mtk][ntq]
    float dinv[4];
    {
        const float* cw = cmb + (size_t)((b % nw) * NH + h) * 4096;
        #pragma unroll
        for (int ntq = 0; ntq < 4; ++ntq) {
            f32x4 s[4];
            #pragma unroll
            for (int mtk = 0; mtk < 4; ++mtk)
                s[mtk] = *(const f32x4*)(cw + (ntq * 16 + c) * 64 + mtk * 16 + g * 4);
            #pragma unroll
            for (int mtk = 0; mtk < 4; ++mtk) {
                s[mtk] = MFMA16(asi(kp[0][mtk]), asi(qp[0][ntq]), s[mtk]);
                s[mtk] = MFMA16(asi(kp[1][mtk]), asi(qp[1][ntq]), s[mtk]);
            }
            float m = s[0][0];
            #pragma unroll
            for (int mtk = 0; mtk < 4; ++mtk)
                #pragma unroll
                for (int r = 0; r < 4; ++r) m = fmaxf(m, s[mtk][r]);
            m = fmaxf(m, __shfl_xor(m, 16));
            m = fmaxf(m, __shfl_xor(m, 32));
            float sum = 0.f;
            #pragma unroll
            for (int mtk = 0; mtk < 4; ++mtk)
                #pragma unroll
                for (int r = 0; r < 4; ++r) {
                    float p = __expf(s[mtk][r] - m);
                    s[mtk][r] = p;
                    sum += p;
                }
            sum += __shfl_xor(sum, 16);
            sum += __shfl_xor(sum, 32);
            dinv[ntq] = 1.f / sum;
            #pragma unroll
            for (int mtk = 0; mtk < 4; ++mtk) pp[mtk][ntq] = pk4(s[mtk]);
        }
    }

    // ---- O^T = vT . P^T (K=16 MFMA, operands straight from vp/pp) ----
    f32x4 o[2][4];
    {
        #pragma unroll
        for (int mtd = 0; mtd < 2; ++mtd)
            #pragma unroll
            for (int ntq = 0; ntq < 4; ++ntq) o[mtd][ntq] = (f32x4){0.f, 0.f, 0.f, 0.f};
        #pragma unroll
        for (int mtk = 0; mtk < 4; ++mtk)
            #pragma unroll
            for (int mtd = 0; mtd < 2; ++mtd)
                #pragma unroll
                for (int ntq = 0; ntq < 4; ++ntq)
                    o[mtd][ntq] = MFMA16(asi(vp[mtk][mtd]), asi(pp[mtk][ntq]), o[mtd][ntq]);
        #pragma unroll
        for (int mtd = 0; mtd < 2; ++mtd)
            #pragma unroll
            for (int ntq = 0; ntq < 4; ++ntq)
                #pragma unroll
                for (int r = 0; r < 4; ++r) o[mtd][ntq][r] *= dinv[ntq];
    }

    __syncthreads();   // all waves done with x region; reuse as ao exchange
    // ao[tok][d] bf16, 16B-granule swizzle ^ (c&15)
    #pragma unroll
    for (int mtd = 0; mtd < 2; ++mtd)
        #pragma unroll
        for (int ntq = 0; ntq < 4; ++ntq) {
            const int byte = (ntq*16 + c)*256 + ((((h*4 + 2*mtd + (g>>1)) ^ c) & 15) << 4) + ((g&1) << 3);
            *(bf16x4*)(smem + byte) = pk4(o[mtd][ntq]);
        }
    __syncthreads();

    // ---- out^T = Wp . ao^T : wave owns 32 output cols; f32x4 stores ----
    {
        f32x4 po[2][4];
        #pragma unroll
        for (int mtO = 0; mtO < 2; ++mtO) {
            const f32x4 pb4 = *(const f32x4*)(proj_b + wave * 32 + mtO * 16 + g * 4);
            #pragma unroll
            for (int nt = 0; nt < 4; ++nt) po[mtO][nt] = pb4;
        }
        #pragma unroll
        for (int ks = 0; ks < 4; ++ks) {
            bf16x8 w0 = *(const bf16x8*)(projw + (wave * 32 +  0 + c) * DIM + ks * 32 + g * 8);
            bf16x8 w1 = *(const bf16x8*)(projw + (wave * 32 + 16 + c) * DIM + ks * 32 + g * 8);
            bf16x8 aof[4];
            #pragma unroll
            for (int nt = 0; nt < 4; ++nt)
                aof[nt] = *(const bf16x8*)(smem + (nt*16 + c)*256 + ((((ks*4 + g) ^ c) & 15) << 4));
            #pragma unroll
            for (int nt = 0; nt < 4; ++nt) {
                po[0][nt] = MFMA32(w0, aof[nt], po[0][nt]);
                po[1][nt] = MFMA32(w1, aof[nt], po[1][nt]);
            }
        }
        float* og = out + (size_t)b * (NTOK * DIM);
        #pragma unroll
        for (int nt = 0; nt < 4; ++nt) {
            const int tok = nt * 16 + c;
            if (tok < NTOK) {
                #pragma unroll
                for (int mtO = 0; mtO < 2; ++mtO)
                    *(f32x4*)(og + tok * DIM + wave * 32 + mtO * 16 + g * 4) = po[mtO][nt];
            }
        }
    }
    #undef LDX
}

extern "C" void kernel_launch(void* const* d_in, const int* in_sizes, int n_in,
                              void* d_out, int out_size, void* d_ws, size_t ws_size,
                              hipStream_t stream) {
    (void)n_in; (void)out_size; (void)ws_size;
    const float* x          = (const float*)d_in[0];
    const float* mask       = (const float*)d_in[1];
    const float* qkv_w      = (const float*)d_in[2];
    const float* qkv_b      = (const float*)d_in[3];
    const float* proj_w     = (const float*)d_in[4];
    const float* proj_b     = (const float*)d_in[5];
    const float* bias_table = (const float*)d_in[6];
    const int*   rel_index  = (const int*)d_in[7];
    float* out = (float*)d_out;

    char* ws = (char*)d_ws;
    bfloat_t* qkvw_b  = (bfloat_t*)ws;              // 98304 B
    bfloat_t* projw_b = (bfloat_t*)(ws + 98304);    // 32768 B
    float*    cmb     = (float*)(ws + 131072);      // nw*NH*64*64*4 B

    const int B  = in_sizes[0] / (NTOK * DIM);
    const int nw = in_sizes[1] / (NTOK * NTOK);

    prep_weights<<<dim3((QKVN * DIM + 255) / 256), dim3(256), 0, stream>>>(qkv_w, proj_w, qkvw_b, projw_b);
    prep_cmb<<<dim3(nw * NH), dim3(256), 0, stream>>>(mask, bias_table, rel_index, cmb);
    win_attn<<<dim3(B), dim3(256), 0, stream>>>(x, qkv_b, proj_b, qkvw_b, projw_b, cmb, out, nw);
}

// Round 8
// 203.371 us; speedup vs baseline: 2.1526x; 1.5223x over previous
//
#include <hip/hip_runtime.h>
#include <hip/hip_bf16.h>
#include <stdint.h>

#define NTOK 49
#define DIM  128
#define NH   4
#define QKVN 384
#define SCALE 0.17677669529663687f

typedef __bf16 bfloat_t;
typedef bfloat_t bf16x8 __attribute__((ext_vector_type(8)));
typedef bfloat_t bf16x4 __attribute__((ext_vector_type(4)));
typedef short    s16x4  __attribute__((ext_vector_type(4)));
typedef float    f32x4  __attribute__((ext_vector_type(4)));

#define MFMA32(a, b, c) __builtin_amdgcn_mfma_f32_16x16x32_bf16(a, b, c, 0, 0, 0)
#define MFMA16(a, b, c) __builtin_amdgcn_mfma_f32_16x16x16bf16_1k(a, b, c, 0, 0, 0)

static __device__ __forceinline__ bf16x4 pk4(f32x4 a) {
    bf16x4 r = { (bfloat_t)a[0], (bfloat_t)a[1], (bfloat_t)a[2], (bfloat_t)a[3] };
    return r;
}
static __device__ __forceinline__ s16x4 asi(bf16x4 v) {
    return __builtin_bit_cast(s16x4, v);
}

__global__ void prep_weights(const float* __restrict__ qkvw,
                             const float* __restrict__ projw,
                             bfloat_t* __restrict__ qkvw_b,
                             bfloat_t* __restrict__ projw_b) {
    int i = blockIdx.x * 256 + threadIdx.x;
    if (i < QKVN * DIM) qkvw_b[i] = (bfloat_t)qkvw[i];
    if (i < DIM * DIM)  projw_b[i] = (bfloat_t)projw[i];
}

// cmb[w][h][tok_q(64)][tok_k(64)] = bias + mask; tok_k>=49 -> -1e30; tok_q>=49 -> 0
__global__ void prep_cmb(const float* __restrict__ mask,
                         const float* __restrict__ bias_table,
                         const int* __restrict__ rel_index,
                         float* __restrict__ cmb) {
    int wh = blockIdx.x;            // w*NH + h
    int w = wh >> 2, h = wh & 3;
    for (int idx = threadIdx.x; idx < 4096; idx += 256) {
        int row = idx >> 6, col = idx & 63;   // row=tok_q, col=tok_k
        float v;
        if (col >= NTOK)      v = -1e30f;
        else if (row >= NTOK) v = 0.f;
        else v = bias_table[rel_index[row * NTOK + col] * NH + h]
               + mask[(w * NTOK + row) * NTOK + col];
        cmb[(size_t)wh * 4096 + idx] = v;
    }
}

// One block = one window; wave = head. Per-head tensors register-chained via
// 16x16x16 MFMA (C/D layout == A/B operand layout). Phase order chosen for
// minimal register liveness (R7 lesson: >~100 live regs at 4 blocks/CU spills):
//   q -> k -> S+softmax(pp) -> v -> PV   (v deferred so vp doesn't overlap qp/kp)
// LDS: x tile 16KB (swizzled), overlaid by ao exchange after PV. 3 barriers.
__global__ __launch_bounds__(256, 4)
void win_attn(const float* __restrict__ x,
              const float* __restrict__ qkv_b,
              const float* __restrict__ proj_b,
              const bfloat_t* __restrict__ qkvw,
              const bfloat_t* __restrict__ projw,
              const float* __restrict__ cmb,
              float* __restrict__ out, int nw) {
    __shared__ __align__(16) char smem[16384];
    const int b    = blockIdx.x;
    const int tid  = threadIdx.x;
    const int wave = tid >> 6;
    const int lane = tid & 63;
    const int g = lane >> 4;
    const int c = lane & 15;
    const int h = wave;

    // ---- stage x -> LDS bf16 [64 tok][128 d], 16B-granule XOR swizzle ----
    {
        const float* xb = x + (size_t)b * (NTOK * DIM);
        #pragma unroll
        for (int i = 0; i < 8; ++i) {
            const int s = tid + i * 256;            // 0..2047 b64 slots
            const int row = s >> 5, col4 = (s & 31) * 4;
            f32x4 v = (row < NTOK) ? *(const f32x4*)(xb + row * DIM + col4)
                                   : (f32x4){0.f, 0.f, 0.f, 0.f};
            *(bf16x4*)(smem + row * 256 + ((col4 * 2) ^ ((row & 7) << 4))) = pk4(v);
        }
    }
    __syncthreads();

    // x A-frag (K=32): [tok=t*16+c][d = ks*32 + g*8 .. +7]
    #define LDX(t, ks) (*(const bf16x8*)(smem + ((t)*16 + c) * 256 + \
                        (((ks)*64 + g*16) ^ ((c & 7) << 4))))

    bf16x4 qp[2][4], kp[2][4];   // packed frags, chunk layout = C/D layout

    // ---- q^T = Wq_h . x^T : D[m=d(2 tiles)][n=tok(4 tiles)] ----
    {
        f32x4 acc[2][4];
        #pragma unroll
        for (int mtd = 0; mtd < 2; ++mtd) {
            const f32x4 qb4 = *(const f32x4*)(qkv_b + h * 32 + mtd * 16 + g * 4);
            #pragma unroll
            for (int nt = 0; nt < 4; ++nt) acc[mtd][nt] = qb4;
        }
        #pragma unroll
        for (int ks = 0; ks < 4; ++ks) {
            bf16x8 w0 = *(const bf16x8*)(qkvw + (h * 32 +  0 + c) * DIM + ks * 32 + g * 8);
            bf16x8 w1 = *(const bf16x8*)(qkvw + (h * 32 + 16 + c) * DIM + ks * 32 + g * 8);
            #pragma unroll
            for (int nt = 0; nt < 4; ++nt) {
                bf16x8 a = LDX(nt, ks);
                acc[0][nt] = MFMA32(w0, a, acc[0][nt]);
                acc[1][nt] = MFMA32(w1, a, acc[1][nt]);
            }
        }
        #pragma unroll
        for (int ds = 0; ds < 2; ++ds)
            #pragma unroll
            for (int nt = 0; nt < 4; ++nt) {
                f32x4 a = acc[ds][nt];
                f32x4 sc = { a[0]*SCALE, a[1]*SCALE, a[2]*SCALE, a[3]*SCALE };
                qp[ds][nt] = pk4(sc);
            }
    }

    // ---- k^T = Wk_h . x^T ----
    {
        f32x4 acc[2][4];
        #pragma unroll
        for (int mtd = 0; mtd < 2; ++mtd) {
            const f32x4 kb4 = *(const f32x4*)(qkv_b + DIM + h * 32 + mtd * 16 + g * 4);
            #pragma unroll
            for (int nt = 0; nt < 4; ++nt) acc[mtd][nt] = kb4;
        }
        #pragma unroll
        for (int ks = 0; ks < 4; ++ks) {
            bf16x8 w0 = *(const bf16x8*)(qkvw + (DIM + h * 32 +  0 + c) * DIM + ks * 32 + g * 8);
            bf16x8 w1 = *(const bf16x8*)(qkvw + (DIM + h * 32 + 16 + c) * DIM + ks * 32 + g * 8);
            #pragma unroll
            for (int nt = 0; nt < 4; ++nt) {
                bf16x8 a = LDX(nt, ks);
                acc[0][nt] = MFMA32(w0, a, acc[0][nt]);
                acc[1][nt] = MFMA32(w1, a, acc[1][nt]);
            }
        }
        #pragma unroll
        for (int ds = 0; ds < 2; ++ds)
            #pragma unroll
            for (int nt = 0; nt < 4; ++nt) kp[ds][nt] = pk4(acc[ds][nt]);
    }

    // ---- S^T = k . q^T (K=16 MFMA, operands straight from qp/kp), softmax ----
    bf16x4 pp[4][4];         // packed P frags [mtk][ntq]
    float dinv[4];
    {
        const float* cw = cmb + (size_t)((b % nw) * NH + h) * 4096;
        #pragma unroll
        for (int ntq = 0; ntq < 4; ++ntq) {
            f32x4 s[4];
            #pragma unroll
            for (int mtk = 0; mtk < 4; ++mtk)
                s[mtk] = *(const f32x4*)(cw + (ntq * 16 + c) * 64 + mtk * 16 + g * 4);
            #pragma unroll
            for (int mtk = 0; mtk < 4; ++mtk) {
                s[mtk] = MFMA16(asi(kp[0][mtk]), asi(qp[0][ntq]), s[mtk]);
                s[mtk] = MFMA16(asi(kp[1][mtk]), asi(qp[1][ntq]), s[mtk]);
            }
            float m = s[0][0];
            #pragma unroll
            for (int mtk = 0; mtk < 4; ++mtk)
                #pragma unroll
                for (int r = 0; r < 4; ++r) m = fmaxf(m, s[mtk][r]);
            m = fmaxf(m, __shfl_xor(m, 16));
            m = fmaxf(m, __shfl_xor(m, 32));
            float sum = 0.f;
            #pragma unroll
            for (int mtk = 0; mtk < 4; ++mtk)
                #pragma unroll
                for (int r = 0; r < 4; ++r) {
                    float p = __expf(s[mtk][r] - m);
                    s[mtk][r] = p;
                    sum += p;
                }
            sum += __shfl_xor(sum, 16);
            sum += __shfl_xor(sum, 32);
            dinv[ntq] = 1.f / sum;
            #pragma unroll
            for (int mtk = 0; mtk < 4; ++mtk) pp[mtk][ntq] = pk4(s[mtk]);
        }
    }

    // ---- v = x . Wv_h^T : D[m=tok(4 tiles)][n=d(2 tiles)] (deferred; x still in LDS) ----
    bf16x4 vp[4][2];
    {
        f32x4 acc[4][2];
        #pragma unroll
        for (int nt = 0; nt < 2; ++nt) {
            const float vb = qkv_b[2 * DIM + h * 32 + nt * 16 + c];
            #pragma unroll
            for (int mt = 0; mt < 4; ++mt) acc[mt][nt] = (f32x4){vb, vb, vb, vb};
        }
        #pragma unroll
        for (int ks = 0; ks < 4; ++ks) {
            bf16x8 w0 = *(const bf16x8*)(qkvw + (2 * DIM + h * 32 +  0 + c) * DIM + ks * 32 + g * 8);
            bf16x8 w1 = *(const bf16x8*)(qkvw + (2 * DIM + h * 32 + 16 + c) * DIM + ks * 32 + g * 8);
            #pragma unroll
            for (int mt = 0; mt < 4; ++mt) {
                bf16x8 a = LDX(mt, ks);
                acc[mt][0] = MFMA32(a, w0, acc[mt][0]);
                acc[mt][1] = MFMA32(a, w1, acc[mt][1]);
            }
        }
        #pragma unroll
        for (int mt = 0; mt < 4; ++mt)
            #pragma unroll
            for (int nt = 0; nt < 2; ++nt) vp[mt][nt] = pk4(acc[mt][nt]);
    }

    // ---- O^T = vT . P^T (K=16 MFMA, operands straight from vp/pp) ----
    f32x4 o[2][4];
    {
        #pragma unroll
        for (int mtd = 0; mtd < 2; ++mtd)
            #pragma unroll
            for (int ntq = 0; ntq < 4; ++ntq) o[mtd][ntq] = (f32x4){0.f, 0.f, 0.f, 0.f};
        #pragma unroll
        for (int mtk = 0; mtk < 4; ++mtk)
            #pragma unroll
            for (int mtd = 0; mtd < 2; ++mtd)
                #pragma unroll
                for (int ntq = 0; ntq < 4; ++ntq)
                    o[mtd][ntq] = MFMA16(asi(vp[mtk][mtd]), asi(pp[mtk][ntq]), o[mtd][ntq]);
        #pragma unroll
        for (int mtd = 0; mtd < 2; ++mtd)
            #pragma unroll
            for (int ntq = 0; ntq < 4; ++ntq)
                #pragma unroll
                for (int r = 0; r < 4; ++r) o[mtd][ntq][r] *= dinv[ntq];
    }

    __syncthreads();   // all waves done with x region; reuse as ao exchange
    // ao[tok][d] bf16, 16B-granule swizzle ^ (c&15)
    #pragma unroll
    for (int mtd = 0; mtd < 2; ++mtd)
        #pragma unroll
        for (int ntq = 0; ntq < 4; ++ntq) {
            const int byte = (ntq*16 + c)*256 + ((((h*4 + 2*mtd + (g>>1)) ^ c) & 15) << 4) + ((g&1) << 3);
            *(bf16x4*)(smem + byte) = pk4(o[mtd][ntq]);
        }
    __syncthreads();

    // ---- out^T = Wp . ao^T : wave owns 32 output cols; f32x4 stores ----
    {
        f32x4 po[2][4];
        #pragma unroll
        for (int mtO = 0; mtO < 2; ++mtO) {
            const f32x4 pb4 = *(const f32x4*)(proj_b + wave * 32 + mtO * 16 + g * 4);
            #pragma unroll
            for (int nt = 0; nt < 4; ++nt) po[mtO][nt] = pb4;
        }
        #pragma unroll
        for (int ks = 0; ks < 4; ++ks) {
            bf16x8 w0 = *(const bf16x8*)(projw + (wave * 32 +  0 + c) * DIM + ks * 32 + g * 8);
            bf16x8 w1 = *(const bf16x8*)(projw + (wave * 32 + 16 + c) * DIM + ks * 32 + g * 8);
            bf16x8 aof[4];
            #pragma unroll
            for (int nt = 0; nt < 4; ++nt)
                aof[nt] = *(const bf16x8*)(smem + (nt*16 + c)*256 + ((((ks*4 + g) ^ c) & 15) << 4));
            #pragma unroll
            for (int nt = 0; nt < 4; ++nt) {
                po[0][nt] = MFMA32(w0, aof[nt], po[0][nt]);
                po[1][nt] = MFMA32(w1, aof[nt], po[1][nt]);
            }
        }
        float* og = out + (size_t)b * (NTOK * DIM);
        #pragma unroll
        for (int nt = 0; nt < 4; ++nt) {
            const int tok = nt * 16 + c;
            if (tok < NTOK) {
                #pragma unroll
                for (int mtO = 0; mtO < 2; ++mtO)
                    *(f32x4*)(og + tok * DIM + wave * 32 + mtO * 16 + g * 4) = po[mtO][nt];
            }
        }
    }
    #undef LDX
}

extern "C" void kernel_launch(void* const* d_in, const int* in_sizes, int n_in,
                              void* d_out, int out_size, void* d_ws, size_t ws_size,
                              hipStream_t stream) {
    (void)n_in; (void)out_size; (void)ws_size;
    const float* x          = (const float*)d_in[0];
    const float* mask       = (const float*)d_in[1];
    const float* qkv_w      = (const float*)d_in[2];
    const float* qkv_b      = (const float*)d_in[3];
    const float* proj_w     = (const float*)d_in[4];
    const float* proj_b     = (const float*)d_in[5];
    const float* bias_table = (const float*)d_in[6];
    const int*   rel_index  = (const int*)d_in[7];
    float* out = (float*)d_out;

    char* ws = (char*)d_ws;
    bfloat_t* qkvw_b  = (bfloat_t*)ws;              // 98304 B
    bfloat_t* projw_b = (bfloat_t*)(ws + 98304);    // 32768 B
    float*    cmb     = (float*)(ws + 131072);      // nw*NH*64*64*4 B

    const int B  = in_sizes[0] / (NTOK * DIM);
    const int nw = in_sizes[1] / (NTOK * NTOK);

    prep_weights<<<dim3((QKVN * DIM + 255) / 256), dim3(256), 0, stream>>>(qkv_w, proj_w, qkvw_b, projw_b);
    prep_cmb<<<dim3(nw * NH), dim3(256), 0, stream>>>(mask, bias_table, rel_index, cmb);
    win_attn<<<dim3(B), dim3(256), 0, stream>>>(x, qkv_b, proj_b, qkvw_b, projw_b, cmb, out, nw);
}

// Round 9
// 196.954 us; speedup vs baseline: 2.2228x; 1.0326x over previous
//
#include <hip/hip_runtime.h>
#include <hip/hip_bf16.h>
#include <stdint.h>

#define NTOK 49
#define DIM  128
#define NH   4
#define QKVN 384
#define SCALE 0.17677669529663687f

typedef __bf16 bfloat_t;
typedef bfloat_t bf16x8 __attribute__((ext_vector_type(8)));
typedef bfloat_t bf16x4 __attribute__((ext_vector_type(4)));
typedef short    s16x4  __attribute__((ext_vector_type(4)));
typedef float    f32x4  __attribute__((ext_vector_type(4)));

#define MFMA32(a, b, c) __builtin_amdgcn_mfma_f32_16x16x32_bf16(a, b, c, 0, 0, 0)
#define MFMA16(a, b, c) __builtin_amdgcn_mfma_f32_16x16x16bf16_1k(a, b, c, 0, 0, 0)

static __device__ __forceinline__ bf16x4 pk4(f32x4 a) {
    bf16x4 r = { (bfloat_t)a[0], (bfloat_t)a[1], (bfloat_t)a[2], (bfloat_t)a[3] };
    return r;
}
static __device__ __forceinline__ s16x4 asi(bf16x4 v) {
    return __builtin_bit_cast(s16x4, v);
}

__global__ void prep_weights(const float* __restrict__ qkvw,
                             const float* __restrict__ projw,
                             bfloat_t* __restrict__ qkvw_b,
                             bfloat_t* __restrict__ projw_b) {
    int i = blockIdx.x * 256 + threadIdx.x;
    if (i < QKVN * DIM) qkvw_b[i] = (bfloat_t)qkvw[i];
    if (i < DIM * DIM)  projw_b[i] = (bfloat_t)projw[i];
}

// cmb[w][h][tok_q(64)][tok_k(64)] = bias + mask; tok_k>=49 -> -1e30; tok_q>=49 -> 0
__global__ void prep_cmb(const float* __restrict__ mask,
                         const float* __restrict__ bias_table,
                         const int* __restrict__ rel_index,
                         float* __restrict__ cmb) {
    int wh = blockIdx.x;            // w*NH + h
    int w = wh >> 2, h = wh & 3;
    for (int idx = threadIdx.x; idx < 4096; idx += 256) {
        int row = idx >> 6, col = idx & 63;   // row=tok_q, col=tok_k
        float v;
        if (col >= NTOK)      v = -1e30f;
        else if (row >= NTOK) v = 0.f;
        else v = bias_table[rel_index[row * NTOK + col] * NH + h]
               + mask[(w * NTOK + row) * NTOK + col];
        cmb[(size_t)wh * 4096 + idx] = v;
    }
}

// One block = one window; wave = head. Register-chained MFMA pipeline
// (16x16x16 C/D layout == A/B operand layout). R9: S+softmax+PV fused per
// tok_q column tile so P is a transient 8-reg pa[4], O packed to bf16
// immediately -> peak liveness ~95 regs, fits 4 blocks/CU without spill
// (R4: pp+o long-lived = ~115 live -> 150MB spill; R8 v-late: worse).
// LDS: x tile 16KB (swizzled), overlaid by ao exchange after PV. 3 barriers.
__global__ __launch_bounds__(256, 4)
void win_attn(const float* __restrict__ x,
              const float* __restrict__ qkv_b,
              const float* __restrict__ proj_b,
              const bfloat_t* __restrict__ qkvw,
              const bfloat_t* __restrict__ projw,
              const float* __restrict__ cmb,
              float* __restrict__ out, int nw) {
    __shared__ __align__(16) char smem[16384];
    const int b    = blockIdx.x;
    const int tid  = threadIdx.x;
    const int wave = tid >> 6;
    const int lane = tid & 63;
    const int g = lane >> 4;
    const int c = lane & 15;
    const int h = wave;

    // ---- stage x -> LDS bf16 [64 tok][128 d], 16B-granule XOR swizzle ----
    {
        const float* xb = x + (size_t)b * (NTOK * DIM);
        #pragma unroll
        for (int i = 0; i < 8; ++i) {
            const int s = tid + i * 256;            // 0..2047 b64 slots
            const int row = s >> 5, col4 = (s & 31) * 4;
            f32x4 v = (row < NTOK) ? *(const f32x4*)(xb + row * DIM + col4)
                                   : (f32x4){0.f, 0.f, 0.f, 0.f};
            *(bf16x4*)(smem + row * 256 + ((col4 * 2) ^ ((row & 7) << 4))) = pk4(v);
        }
    }
    __syncthreads();

    // x A-frag (K=32): [tok=t*16+c][d = ks*32 + g*8 .. +7]
    #define LDX(t, ks) (*(const bf16x8*)(smem + ((t)*16 + c) * 256 + \
                        (((ks)*64 + g*16) ^ ((c & 7) << 4))))

    bf16x4 qp[2][4], kp[2][4], vp[4][2];   // packed frags, chunk layout = C/D layout

    // ---- q^T = Wq_h . x^T : D[m=d(2 tiles)][n=tok(4 tiles)] ----
    {
        f32x4 acc[2][4];
        #pragma unroll
        for (int mtd = 0; mtd < 2; ++mtd) {
            const f32x4 qb4 = *(const f32x4*)(qkv_b + h * 32 + mtd * 16 + g * 4);
            #pragma unroll
            for (int nt = 0; nt < 4; ++nt) acc[mtd][nt] = qb4;
        }
        #pragma unroll
        for (int ks = 0; ks < 4; ++ks) {
            bf16x8 w0 = *(const bf16x8*)(qkvw + (h * 32 +  0 + c) * DIM + ks * 32 + g * 8);
            bf16x8 w1 = *(const bf16x8*)(qkvw + (h * 32 + 16 + c) * DIM + ks * 32 + g * 8);
            #pragma unroll
            for (int nt = 0; nt < 4; ++nt) {
                bf16x8 a = LDX(nt, ks);
                acc[0][nt] = MFMA32(w0, a, acc[0][nt]);
                acc[1][nt] = MFMA32(w1, a, acc[1][nt]);
            }
        }
        #pragma unroll
        for (int ds = 0; ds < 2; ++ds)
            #pragma unroll
            for (int nt = 0; nt < 4; ++nt) {
                f32x4 a = acc[ds][nt];
                f32x4 sc = { a[0]*SCALE, a[1]*SCALE, a[2]*SCALE, a[3]*SCALE };
                qp[ds][nt] = pk4(sc);
            }
    }

    // ---- k^T = Wk_h . x^T ----
    {
        f32x4 acc[2][4];
        #pragma unroll
        for (int mtd = 0; mtd < 2; ++mtd) {
            const f32x4 kb4 = *(const f32x4*)(qkv_b + DIM + h * 32 + mtd * 16 + g * 4);
            #pragma unroll
            for (int nt = 0; nt < 4; ++nt) acc[mtd][nt] = kb4;
        }
        #pragma unroll
        for (int ks = 0; ks < 4; ++ks) {
            bf16x8 w0 = *(const bf16x8*)(qkvw + (DIM + h * 32 +  0 + c) * DIM + ks * 32 + g * 8);
            bf16x8 w1 = *(const bf16x8*)(qkvw + (DIM + h * 32 + 16 + c) * DIM + ks * 32 + g * 8);
            #pragma unroll
            for (int nt = 0; nt < 4; ++nt) {
                bf16x8 a = LDX(nt, ks);
                acc[0][nt] = MFMA32(w0, a, acc[0][nt]);
                acc[1][nt] = MFMA32(w1, a, acc[1][nt]);
            }
        }
        #pragma unroll
        for (int ds = 0; ds < 2; ++ds)
            #pragma unroll
            for (int nt = 0; nt < 4; ++nt) kp[ds][nt] = pk4(acc[ds][nt]);
    }

    // ---- v = x . Wv_h^T : D[m=tok(4 tiles)][n=d(2 tiles)] ----
    {
        f32x4 acc[4][2];
        #pragma unroll
        for (int nt = 0; nt < 2; ++nt) {
            const float vb = qkv_b[2 * DIM + h * 32 + nt * 16 + c];
            #pragma unroll
            for (int mt = 0; mt < 4; ++mt) acc[mt][nt] = (f32x4){vb, vb, vb, vb};
        }
        #pragma unroll
        for (int ks = 0; ks < 4; ++ks) {
            bf16x8 w0 = *(const bf16x8*)(qkvw + (2 * DIM + h * 32 +  0 + c) * DIM + ks * 32 + g * 8);
            bf16x8 w1 = *(const bf16x8*)(qkvw + (2 * DIM + h * 32 + 16 + c) * DIM + ks * 32 + g * 8);
            #pragma unroll
            for (int mt = 0; mt < 4; ++mt) {
                bf16x8 a = LDX(mt, ks);
                acc[mt][0] = MFMA32(a, w0, acc[mt][0]);
                acc[mt][1] = MFMA32(a, w1, acc[mt][1]);
            }
        }
        #pragma unroll
        for (int mt = 0; mt < 4; ++mt)
            #pragma unroll
            for (int nt = 0; nt < 2; ++nt) vp[mt][nt] = pk4(acc[mt][nt]);
    }

    // ---- fused per-ntq: S^T tile -> softmax -> PV -> packed O (bf16) ----
    bf16x4 op[2][4];     // packed O^T frags [mtd][ntq], ready for ao write
    {
        const float* cw = cmb + (size_t)((b % nw) * NH + h) * 4096;
        #pragma unroll
        for (int ntq = 0; ntq < 4; ++ntq) {
            f32x4 s[4];
            #pragma unroll
            for (int mtk = 0; mtk < 4; ++mtk)
                s[mtk] = *(const f32x4*)(cw + (ntq * 16 + c) * 64 + mtk * 16 + g * 4);
            #pragma unroll
            for (int mtk = 0; mtk < 4; ++mtk) {
                s[mtk] = MFMA16(asi(kp[0][mtk]), asi(qp[0][ntq]), s[mtk]);
                s[mtk] = MFMA16(asi(kp[1][mtk]), asi(qp[1][ntq]), s[mtk]);
            }
            float m = s[0][0];
            #pragma unroll
            for (int mtk = 0; mtk < 4; ++mtk)
                #pragma unroll
                for (int r = 0; r < 4; ++r) m = fmaxf(m, s[mtk][r]);
            m = fmaxf(m, __shfl_xor(m, 16));
            m = fmaxf(m, __shfl_xor(m, 32));
            float sum = 0.f;
            #pragma unroll
            for (int mtk = 0; mtk < 4; ++mtk)
                #pragma unroll
                for (int r = 0; r < 4; ++r) {
                    float p = __expf(s[mtk][r] - m);
                    s[mtk][r] = p;
                    sum += p;
                }
            sum += __shfl_xor(sum, 16);
            sum += __shfl_xor(sum, 32);
            const float dinv = 1.f / sum;

            bf16x4 pa[4];
            #pragma unroll
            for (int mtk = 0; mtk < 4; ++mtk) pa[mtk] = pk4(s[mtk]);

            f32x4 o0 = {0.f, 0.f, 0.f, 0.f}, o1 = {0.f, 0.f, 0.f, 0.f};
            #pragma unroll
            for (int mtk = 0; mtk < 4; ++mtk) {
                o0 = MFMA16(asi(vp[mtk][0]), asi(pa[mtk]), o0);
                o1 = MFMA16(asi(vp[mtk][1]), asi(pa[mtk]), o1);
            }
            f32x4 so0 = { o0[0]*dinv, o0[1]*dinv, o0[2]*dinv, o0[3]*dinv };
            f32x4 so1 = { o1[0]*dinv, o1[1]*dinv, o1[2]*dinv, o1[3]*dinv };
            op[0][ntq] = pk4(so0);
            op[1][ntq] = pk4(so1);
        }
    }

    __syncthreads();   // all waves done with x region; reuse as ao exchange
    // ao[tok][d] bf16, 16B-granule swizzle ^ (c&15)
    #pragma unroll
    for (int mtd = 0; mtd < 2; ++mtd)
        #pragma unroll
        for (int ntq = 0; ntq < 4; ++ntq) {
            const int byte = (ntq*16 + c)*256 + ((((h*4 + 2*mtd + (g>>1)) ^ c) & 15) << 4) + ((g&1) << 3);
            *(bf16x4*)(smem + byte) = op[mtd][ntq];
        }
    __syncthreads();

    // ---- out^T = Wp . ao^T : wave owns 32 output cols; f32x4 stores ----
    {
        f32x4 po[2][4];
        #pragma unroll
        for (int mtO = 0; mtO < 2; ++mtO) {
            const f32x4 pb4 = *(const f32x4*)(proj_b + wave * 32 + mtO * 16 + g * 4);
            #pragma unroll
            for (int nt = 0; nt < 4; ++nt) po[mtO][nt] = pb4;
        }
        #pragma unroll
        for (int ks = 0; ks < 4; ++ks) {
            bf16x8 w0 = *(const bf16x8*)(projw + (wave * 32 +  0 + c) * DIM + ks * 32 + g * 8);
            bf16x8 w1 = *(const bf16x8*)(projw + (wave * 32 + 16 + c) * DIM + ks * 32 + g * 8);
            bf16x8 aof[4];
            #pragma unroll
            for (int nt = 0; nt < 4; ++nt)
                aof[nt] = *(const bf16x8*)(smem + (nt*16 + c)*256 + ((((ks*4 + g) ^ c) & 15) << 4));
            #pragma unroll
            for (int nt = 0; nt < 4; ++nt) {
                po[0][nt] = MFMA32(w0, aof[nt], po[0][nt]);
                po[1][nt] = MFMA32(w1, aof[nt], po[1][nt]);
            }
        }
        float* og = out + (size_t)b * (NTOK * DIM);
        #pragma unroll
        for (int nt = 0; nt < 4; ++nt) {
            const int tok = nt * 16 + c;
            if (tok < NTOK) {
                #pragma unroll
                for (int mtO = 0; mtO < 2; ++mtO)
                    *(f32x4*)(og + tok * DIM + wave * 32 + mtO * 16 + g * 4) = po[mtO][nt];
            }
        }
    }
    #undef LDX
}

extern "C" void kernel_launch(void* const* d_in, const int* in_sizes, int n_in,
                              void* d_out, int out_size, void* d_ws, size_t ws_size,
                              hipStream_t stream) {
    (void)n_in; (void)out_size; (void)ws_size;
    const float* x          = (const float*)d_in[0];
    const float* mask       = (const float*)d_in[1];
    const float* qkv_w      = (const float*)d_in[2];
    const float* qkv_b      = (const float*)d_in[3];
    const float* proj_w     = (const float*)d_in[4];
    const float* proj_b     = (const float*)d_in[5];
    const float* bias_table = (const float*)d_in[6];
    const int*   rel_index  = (const int*)d_in[7];
    float* out = (float*)d_out;

    char* ws = (char*)d_ws;
    bfloat_t* qkvw_b  = (bfloat_t*)ws;              // 98304 B
    bfloat_t* projw_b = (bfloat_t*)(ws + 98304);    // 32768 B
    float*    cmb     = (float*)(ws + 131072);      // nw*NH*64*64*4 B

    const int B  = in_sizes[0] / (NTOK * DIM);
    const int nw = in_sizes[1] / (NTOK * NTOK);

    prep_weights<<<dim3((QKVN * DIM + 255) / 256), dim3(256), 0, stream>>>(qkv_w, proj_w, qkvw_b, projw_b);
    prep_cmb<<<dim3(nw * NH), dim3(256), 0, stream>>>(mask, bias_table, rel_index, cmb);
    win_attn<<<dim3(B), dim3(256), 0, stream>>>(x, qkv_b, proj_b, qkvw_b, projw_b, cmb, out, nw);
}

// Round 10
// 152.310 us; speedup vs baseline: 2.8743x; 1.2931x over previous
//
#include <hip/hip_runtime.h>
#include <hip/hip_bf16.h>
#include <stdint.h>

#define NTOK 49
#define DIM  128
#define NH   4
#define QKVN 384
#define SCALE 0.17677669529663687f

typedef __bf16 bfloat_t;
typedef bfloat_t bf16x8 __attribute__((ext_vector_type(8)));
typedef bfloat_t bf16x4 __attribute__((ext_vector_type(4)));
typedef short    s16x4  __attribute__((ext_vector_type(4)));
typedef float    f32x4  __attribute__((ext_vector_type(4)));

#define MFMA32(a, b, c) __builtin_amdgcn_mfma_f32_16x16x32_bf16(a, b, c, 0, 0, 0)
#define MFMA16(a, b, c) __builtin_amdgcn_mfma_f32_16x16x16bf16_1k(a, b, c, 0, 0, 0)

static __device__ __forceinline__ bf16x4 pk4(f32x4 a) {
    bf16x4 r = { (bfloat_t)a[0], (bfloat_t)a[1], (bfloat_t)a[2], (bfloat_t)a[3] };
    return r;
}
static __device__ __forceinline__ s16x4 asi(bf16x4 v) {
    return __builtin_bit_cast(s16x4, v);
}

__global__ void prep_weights(const float* __restrict__ qkvw,
                             const float* __restrict__ projw,
                             bfloat_t* __restrict__ qkvw_b,
                             bfloat_t* __restrict__ projw_b) {
    int i = blockIdx.x * 256 + threadIdx.x;
    if (i < QKVN * DIM) qkvw_b[i] = (bfloat_t)qkvw[i];
    if (i < DIM * DIM)  projw_b[i] = (bfloat_t)projw[i];
}

// cmb[w][h][tok_q(64)][tok_k(64)] = bias + mask; tok_k>=49 -> -1e30; tok_q>=49 -> 0
__global__ void prep_cmb(const float* __restrict__ mask,
                         const float* __restrict__ bias_table,
                         const int* __restrict__ rel_index,
                         float* __restrict__ cmb) {
    int wh = blockIdx.x;            // w*NH + h
    int w = wh >> 2, h = wh & 3;
    for (int idx = threadIdx.x; idx < 4096; idx += 256) {
        int row = idx >> 6, col = idx & 63;   // row=tok_q, col=tok_k
        float v;
        if (col >= NTOK)      v = -1e30f;
        else if (row >= NTOK) v = 0.f;
        else v = bias_table[rel_index[row * NTOK + col] * NH + h]
               + mask[(w * NTOK + row) * NTOK + col];
        cmb[(size_t)wh * 4096 + idx] = v;
    }
}

// One block = one window; wave = head. Register-chained MFMA pipeline
// (16x16x16 C/D layout == A/B operand layout). S+softmax+PV fused per tok_q
// column tile (P transient, O packed to bf16 immediately).
// NO __launch_bounds__: forcing a wave cap makes the backend split the unified
// register file into a too-small arch-VGPR half -> scratch spill (R4/R6-R9:
// WRITE 251..714MB vs 100MB output, VGPR report = 512/N/2 each time).
// Natural allocation (~90-110 regs) -> 4 waves/SIMD, zero spill.
// LDS: x tile 16KB (swizzled), overlaid by ao exchange after PV. 3 barriers.
__global__
void win_attn(const float* __restrict__ x,
              const float* __restrict__ qkv_b,
              const float* __restrict__ proj_b,
              const bfloat_t* __restrict__ qkvw,
              const bfloat_t* __restrict__ projw,
              const float* __restrict__ cmb,
              float* __restrict__ out, int nw) {
    __shared__ __align__(16) char smem[16384];
    const int b    = blockIdx.x;
    const int tid  = threadIdx.x;
    const int wave = tid >> 6;
    const int lane = tid & 63;
    const int g = lane >> 4;
    const int c = lane & 15;
    const int h = wave;

    // ---- stage x -> LDS bf16 [64 tok][128 d], 16B-granule XOR swizzle ----
    {
        const float* xb = x + (size_t)b * (NTOK * DIM);
        #pragma unroll
        for (int i = 0; i < 8; ++i) {
            const int s = tid + i * 256;            // 0..2047 b64 slots
            const int row = s >> 5, col4 = (s & 31) * 4;
            f32x4 v = (row < NTOK) ? *(const f32x4*)(xb + row * DIM + col4)
                                   : (f32x4){0.f, 0.f, 0.f, 0.f};
            *(bf16x4*)(smem + row * 256 + ((col4 * 2) ^ ((row & 7) << 4))) = pk4(v);
        }
    }
    __syncthreads();

    // x A-frag (K=32): [tok=t*16+c][d = ks*32 + g*8 .. +7]
    #define LDX(t, ks) (*(const bf16x8*)(smem + ((t)*16 + c) * 256 + \
                        (((ks)*64 + g*16) ^ ((c & 7) << 4))))

    bf16x4 qp[2][4], kp[2][4], vp[4][2];   // packed frags, chunk layout = C/D layout

    // ---- q^T = Wq_h . x^T : D[m=d(2 tiles)][n=tok(4 tiles)] ----
    {
        f32x4 acc[2][4];
        #pragma unroll
        for (int mtd = 0; mtd < 2; ++mtd) {
            const f32x4 qb4 = *(const f32x4*)(qkv_b + h * 32 + mtd * 16 + g * 4);
            #pragma unroll
            for (int nt = 0; nt < 4; ++nt) acc[mtd][nt] = qb4;
        }
        #pragma unroll
        for (int ks = 0; ks < 4; ++ks) {
            bf16x8 w0 = *(const bf16x8*)(qkvw + (h * 32 +  0 + c) * DIM + ks * 32 + g * 8);
            bf16x8 w1 = *(const bf16x8*)(qkvw + (h * 32 + 16 + c) * DIM + ks * 32 + g * 8);
            #pragma unroll
            for (int nt = 0; nt < 4; ++nt) {
                bf16x8 a = LDX(nt, ks);
                acc[0][nt] = MFMA32(w0, a, acc[0][nt]);
                acc[1][nt] = MFMA32(w1, a, acc[1][nt]);
            }
        }
        #pragma unroll
        for (int ds = 0; ds < 2; ++ds)
            #pragma unroll
            for (int nt = 0; nt < 4; ++nt) {
                f32x4 a = acc[ds][nt];
                f32x4 sc = { a[0]*SCALE, a[1]*SCALE, a[2]*SCALE, a[3]*SCALE };
                qp[ds][nt] = pk4(sc);
            }
    }

    // ---- k^T = Wk_h . x^T ----
    {
        f32x4 acc[2][4];
        #pragma unroll
        for (int mtd = 0; mtd < 2; ++mtd) {
            const f32x4 kb4 = *(const f32x4*)(qkv_b + DIM + h * 32 + mtd * 16 + g * 4);
            #pragma unroll
            for (int nt = 0; nt < 4; ++nt) acc[mtd][nt] = kb4;
        }
        #pragma unroll
        for (int ks = 0; ks < 4; ++ks) {
            bf16x8 w0 = *(const bf16x8*)(qkvw + (DIM + h * 32 +  0 + c) * DIM + ks * 32 + g * 8);
            bf16x8 w1 = *(const bf16x8*)(qkvw + (DIM + h * 32 + 16 + c) * DIM + ks * 32 + g * 8);
            #pragma unroll
            for (int nt = 0; nt < 4; ++nt) {
                bf16x8 a = LDX(nt, ks);
                acc[0][nt] = MFMA32(w0, a, acc[0][nt]);
                acc[1][nt] = MFMA32(w1, a, acc[1][nt]);
            }
        }
        #pragma unroll
        for (int ds = 0; ds < 2; ++ds)
            #pragma unroll
            for (int nt = 0; nt < 4; ++nt) kp[ds][nt] = pk4(acc[ds][nt]);
    }

    // ---- v = x . Wv_h^T : D[m=tok(4 tiles)][n=d(2 tiles)] ----
    {
        f32x4 acc[4][2];
        #pragma unroll
        for (int nt = 0; nt < 2; ++nt) {
            const float vb = qkv_b[2 * DIM + h * 32 + nt * 16 + c];
            #pragma unroll
            for (int mt = 0; mt < 4; ++mt) acc[mt][nt] = (f32x4){vb, vb, vb, vb};
        }
        #pragma unroll
        for (int ks = 0; ks < 4; ++ks) {
            bf16x8 w0 = *(const bf16x8*)(qkvw + (2 * DIM + h * 32 +  0 + c) * DIM + ks * 32 + g * 8);
            bf16x8 w1 = *(const bf16x8*)(qkvw + (2 * DIM + h * 32 + 16 + c) * DIM + ks * 32 + g * 8);
            #pragma unroll
            for (int mt = 0; mt < 4; ++mt) {
                bf16x8 a = LDX(mt, ks);
                acc[mt][0] = MFMA32(a, w0, acc[mt][0]);
                acc[mt][1] = MFMA32(a, w1, acc[mt][1]);
            }
        }
        #pragma unroll
        for (int mt = 0; mt < 4; ++mt)
            #pragma unroll
            for (int nt = 0; nt < 2; ++nt) vp[mt][nt] = pk4(acc[mt][nt]);
    }

    // ---- fused per-ntq: S^T tile -> softmax -> PV -> packed O (bf16) ----
    bf16x4 op[2][4];     // packed O^T frags [mtd][ntq], ready for ao write
    {
        const float* cw = cmb + (size_t)((b % nw) * NH + h) * 4096;
        #pragma unroll
        for (int ntq = 0; ntq < 4; ++ntq) {
            f32x4 s[4];
            #pragma unroll
            for (int mtk = 0; mtk < 4; ++mtk)
                s[mtk] = *(const f32x4*)(cw + (ntq * 16 + c) * 64 + mtk * 16 + g * 4);
            #pragma unroll
            for (int mtk = 0; mtk < 4; ++mtk) {
                s[mtk] = MFMA16(asi(kp[0][mtk]), asi(qp[0][ntq]), s[mtk]);
                s[mtk] = MFMA16(asi(kp[1][mtk]), asi(qp[1][ntq]), s[mtk]);
            }
            float m = s[0][0];
            #pragma unroll
            for (int mtk = 0; mtk < 4; ++mtk)
                #pragma unroll
                for (int r = 0; r < 4; ++r) m = fmaxf(m, s[mtk][r]);
            m = fmaxf(m, __shfl_xor(m, 16));
            m = fmaxf(m, __shfl_xor(m, 32));
            float sum = 0.f;
            #pragma unroll
            for (int mtk = 0; mtk < 4; ++mtk)
                #pragma unroll
                for (int r = 0; r < 4; ++r) {
                    float p = __expf(s[mtk][r] - m);
                    s[mtk][r] = p;
                    sum += p;
                }
            sum += __shfl_xor(sum, 16);
            sum += __shfl_xor(sum, 32);
            const float dinv = 1.f / sum;

            bf16x4 pa[4];
            #pragma unroll
            for (int mtk = 0; mtk < 4; ++mtk) pa[mtk] = pk4(s[mtk]);

            f32x4 o0 = {0.f, 0.f, 0.f, 0.f}, o1 = {0.f, 0.f, 0.f, 0.f};
            #pragma unroll
            for (int mtk = 0; mtk < 4; ++mtk) {
                o0 = MFMA16(asi(vp[mtk][0]), asi(pa[mtk]), o0);
                o1 = MFMA16(asi(vp[mtk][1]), asi(pa[mtk]), o1);
            }
            f32x4 so0 = { o0[0]*dinv, o0[1]*dinv, o0[2]*dinv, o0[3]*dinv };
            f32x4 so1 = { o1[0]*dinv, o1[1]*dinv, o1[2]*dinv, o1[3]*dinv };
            op[0][ntq] = pk4(so0);
            op[1][ntq] = pk4(so1);
        }
    }

    __syncthreads();   // all waves done with x region; reuse as ao exchange
    // ao[tok][d] bf16, 16B-granule swizzle ^ (c&15)
    #pragma unroll
    for (int mtd = 0; mtd < 2; ++mtd)
        #pragma unroll
        for (int ntq = 0; ntq < 4; ++ntq) {
            const int byte = (ntq*16 + c)*256 + ((((h*4 + 2*mtd + (g>>1)) ^ c) & 15) << 4) + ((g&1) << 3);
            *(bf16x4*)(smem + byte) = op[mtd][ntq];
        }
    __syncthreads();

    // ---- out^T = Wp . ao^T : wave owns 32 output cols; f32x4 stores ----
    {
        f32x4 po[2][4];
        #pragma unroll
        for (int mtO = 0; mtO < 2; ++mtO) {
            const f32x4 pb4 = *(const f32x4*)(proj_b + wave * 32 + mtO * 16 + g * 4);
            #pragma unroll
            for (int nt = 0; nt < 4; ++nt) po[mtO][nt] = pb4;
        }
        #pragma unroll
        for (int ks = 0; ks < 4; ++ks) {
            bf16x8 w0 = *(const bf16x8*)(projw + (wave * 32 +  0 + c) * DIM + ks * 32 + g * 8);
            bf16x8 w1 = *(const bf16x8*)(projw + (wave * 32 + 16 + c) * DIM + ks * 32 + g * 8);
            bf16x8 aof[4];
            #pragma unroll
            for (int nt = 0; nt < 4; ++nt)
                aof[nt] = *(const bf16x8*)(smem + (nt*16 + c)*256 + ((((ks*4 + g) ^ c) & 15) << 4));
            #pragma unroll
            for (int nt = 0; nt < 4; ++nt) {
                po[0][nt] = MFMA32(w0, aof[nt], po[0][nt]);
                po[1][nt] = MFMA32(w1, aof[nt], po[1][nt]);
            }
        }
        float* og = out + (size_t)b * (NTOK * DIM);
        #pragma unroll
        for (int nt = 0; nt < 4; ++nt) {
            const int tok = nt * 16 + c;
            if (tok < NTOK) {
                #pragma unroll
                for (int mtO = 0; mtO < 2; ++mtO)
                    *(f32x4*)(og + tok * DIM + wave * 32 + mtO * 16 + g * 4) = po[mtO][nt];
            }
        }
    }
    #undef LDX
}

extern "C" void kernel_launch(void* const* d_in, const int* in_sizes, int n_in,
                              void* d_out, int out_size, void* d_ws, size_t ws_size,
                              hipStream_t stream) {
    (void)n_in; (void)out_size; (void)ws_size;
    const float* x          = (const float*)d_in[0];
    const float* mask       = (const float*)d_in[1];
    const float* qkv_w      = (const float*)d_in[2];
    const float* qkv_b      = (const float*)d_in[3];
    const float* proj_w     = (const float*)d_in[4];
    const float* proj_b     = (const float*)d_in[5];
    const float* bias_table = (const float*)d_in[6];
    const int*   rel_index  = (const int*)d_in[7];
    float* out = (float*)d_out;

    char* ws = (char*)d_ws;
    bfloat_t* qkvw_b  = (bfloat_t*)ws;              // 98304 B
    bfloat_t* projw_b = (bfloat_t*)(ws + 98304);    // 32768 B
    float*    cmb     = (float*)(ws + 131072);      // nw*NH*64*64*4 B

    const int B  = in_sizes[0] / (NTOK * DIM);
    const int nw = in_sizes[1] / (NTOK * NTOK);

    prep_weights<<<dim3((QKVN * DIM + 255) / 256), dim3(256), 0, stream>>>(qkv_w, proj_w, qkvw_b, projw_b);
    prep_cmb<<<dim3(nw * NH), dim3(256), 0, stream>>>(mask, bias_table, rel_index, cmb);
    win_attn<<<dim3(B), dim3(256), 0, stream>>>(x, qkv_b, proj_b, qkvw_b, projw_b, cmb, out, nw);
}

// Round 11
// 131.332 us; speedup vs baseline: 3.3334x; 1.1597x over previous
//
#include <hip/hip_runtime.h>
#include <hip/hip_bf16.h>
#include <stdint.h>

#define NTOK 49
#define DIM  128
#define NH   4
#define QKVN 384
#define SCALE 0.17677669529663687f

typedef __bf16 bfloat_t;
typedef bfloat_t bf16x8 __attribute__((ext_vector_type(8)));
typedef bfloat_t bf16x4 __attribute__((ext_vector_type(4)));
typedef short    s16x4  __attribute__((ext_vector_type(4)));
typedef float    f32x4  __attribute__((ext_vector_type(4)));

#define MFMA32(a, b, c) __builtin_amdgcn_mfma_f32_16x16x32_bf16(a, b, c, 0, 0, 0)
#define MFMA16(a, b, c) __builtin_amdgcn_mfma_f32_16x16x16bf16_1k(a, b, c, 0, 0, 0)

static __device__ __forceinline__ bf16x4 pk4(f32x4 a) {
    bf16x4 r = { (bfloat_t)a[0], (bfloat_t)a[1], (bfloat_t)a[2], (bfloat_t)a[3] };
    return r;
}
static __device__ __forceinline__ s16x4 asi(bf16x4 v) {
    return __builtin_bit_cast(s16x4, v);
}

__global__ void prep_weights(const float* __restrict__ qkvw,
                             const float* __restrict__ projw,
                             bfloat_t* __restrict__ qkvw_b,
                             bfloat_t* __restrict__ projw_b) {
    int i = blockIdx.x * 256 + threadIdx.x;
    if (i < QKVN * DIM) qkvw_b[i] = (bfloat_t)qkvw[i];
    if (i < DIM * DIM)  projw_b[i] = (bfloat_t)projw[i];
}

// cmb[w][h][tok_q(64)][tok_k(64)] = bias + mask; tok_k>=49 -> -1e30; tok_q>=49 -> 0
__global__ void prep_cmb(const float* __restrict__ mask,
                         const float* __restrict__ bias_table,
                         const int* __restrict__ rel_index,
                         float* __restrict__ cmb) {
    int wh = blockIdx.x;            // w*NH + h
    int w = wh >> 2, h = wh & 3;
    for (int idx = threadIdx.x; idx < 4096; idx += 256) {
        int row = idx >> 6, col = idx & 63;   // row=tok_q, col=tok_k
        float v;
        if (col >= NTOK)      v = -1e30f;
        else if (row >= NTOK) v = 0.f;
        else v = bias_table[rel_index[row * NTOK + col] * NH + h]
               + mask[(w * NTOK + row) * NTOK + col];
        cmb[(size_t)wh * 4096 + idx] = v;
    }
}

// One block = one window; wave = head. Register-chained MFMA pipeline
// (16x16x16 C/D layout == A/B operand layout). S+softmax+PV fused per tok_q
// tile; O streamed straight to the ao LDS region per tile (no op array).
// launch_bounds(256,3): unified budget ~170/wave -> arch VGPRs ~100, NO spill.
// (4 waves/SIMD forces a 64-arch/64-agpr split; live frags ~80 arch -> the
// persistent 110-225MB scratch traffic of R4/R8-R10.)
// LDS 32KB: x tile [0,16K) swizzled; ao exchange [16K,32K). 2 barriers.
__global__ __launch_bounds__(256, 3)
void win_attn(const float* __restrict__ x,
              const float* __restrict__ qkv_b,
              const float* __restrict__ proj_b,
              const bfloat_t* __restrict__ qkvw,
              const bfloat_t* __restrict__ projw,
              const float* __restrict__ cmb,
              float* __restrict__ out, int nw) {
    __shared__ __align__(16) char smem[32768];
    char* aosm = smem + 16384;
    const int b    = blockIdx.x;
    const int tid  = threadIdx.x;
    const int wave = tid >> 6;
    const int lane = tid & 63;
    const int g = lane >> 4;
    const int c = lane & 15;
    const int h = wave;

    // ---- stage x -> LDS bf16 [64 tok][128 d], 16B-granule XOR swizzle ----
    {
        const float* xb = x + (size_t)b * (NTOK * DIM);
        #pragma unroll
        for (int i = 0; i < 8; ++i) {
            const int s = tid + i * 256;            // 0..2047 b64 slots
            const int row = s >> 5, col4 = (s & 31) * 4;
            f32x4 v = (row < NTOK) ? *(const f32x4*)(xb + row * DIM + col4)
                                   : (f32x4){0.f, 0.f, 0.f, 0.f};
            *(bf16x4*)(smem + row * 256 + ((col4 * 2) ^ ((row & 7) << 4))) = pk4(v);
        }
    }
    __syncthreads();

    // x A-frag (K=32): [tok=t*16+c][d = ks*32 + g*8 .. +7]
    #define LDX(t, ks) (*(const bf16x8*)(smem + ((t)*16 + c) * 256 + \
                        (((ks)*64 + g*16) ^ ((c & 7) << 4))))

    bf16x4 qp[2][4], kp[2][4], vp[4][2];   // packed frags, chunk layout = C/D layout

    // ---- q^T = Wq_h . x^T : D[m=d(2 tiles)][n=tok(4 tiles)] ----
    {
        f32x4 acc[2][4];
        #pragma unroll
        for (int mtd = 0; mtd < 2; ++mtd) {
            const f32x4 qb4 = *(const f32x4*)(qkv_b + h * 32 + mtd * 16 + g * 4);
            #pragma unroll
            for (int nt = 0; nt < 4; ++nt) acc[mtd][nt] = qb4;
        }
        #pragma unroll
        for (int ks = 0; ks < 4; ++ks) {
            bf16x8 w0 = *(const bf16x8*)(qkvw + (h * 32 +  0 + c) * DIM + ks * 32 + g * 8);
            bf16x8 w1 = *(const bf16x8*)(qkvw + (h * 32 + 16 + c) * DIM + ks * 32 + g * 8);
            #pragma unroll
            for (int nt = 0; nt < 4; ++nt) {
                bf16x8 a = LDX(nt, ks);
                acc[0][nt] = MFMA32(w0, a, acc[0][nt]);
                acc[1][nt] = MFMA32(w1, a, acc[1][nt]);
            }
        }
        #pragma unroll
        for (int ds = 0; ds < 2; ++ds)
            #pragma unroll
            for (int nt = 0; nt < 4; ++nt) {
                f32x4 a = acc[ds][nt];
                f32x4 sc = { a[0]*SCALE, a[1]*SCALE, a[2]*SCALE, a[3]*SCALE };
                qp[ds][nt] = pk4(sc);
            }
    }

    // ---- k^T = Wk_h . x^T ----
    {
        f32x4 acc[2][4];
        #pragma unroll
        for (int mtd = 0; mtd < 2; ++mtd) {
            const f32x4 kb4 = *(const f32x4*)(qkv_b + DIM + h * 32 + mtd * 16 + g * 4);
            #pragma unroll
            for (int nt = 0; nt < 4; ++nt) acc[mtd][nt] = kb4;
        }
        #pragma unroll
        for (int ks = 0; ks < 4; ++ks) {
            bf16x8 w0 = *(const bf16x8*)(qkvw + (DIM + h * 32 +  0 + c) * DIM + ks * 32 + g * 8);
            bf16x8 w1 = *(const bf16x8*)(qkvw + (DIM + h * 32 + 16 + c) * DIM + ks * 32 + g * 8);
            #pragma unroll
            for (int nt = 0; nt < 4; ++nt) {
                bf16x8 a = LDX(nt, ks);
                acc[0][nt] = MFMA32(w0, a, acc[0][nt]);
                acc[1][nt] = MFMA32(w1, a, acc[1][nt]);
            }
        }
        #pragma unroll
        for (int ds = 0; ds < 2; ++ds)
            #pragma unroll
            for (int nt = 0; nt < 4; ++nt) kp[ds][nt] = pk4(acc[ds][nt]);
    }

    // ---- v = x . Wv_h^T : D[m=tok(4 tiles)][n=d(2 tiles)] ----
    {
        f32x4 acc[4][2];
        #pragma unroll
        for (int nt = 0; nt < 2; ++nt) {
            const float vb = qkv_b[2 * DIM + h * 32 + nt * 16 + c];
            #pragma unroll
            for (int mt = 0; mt < 4; ++mt) acc[mt][nt] = (f32x4){vb, vb, vb, vb};
        }
        #pragma unroll
        for (int ks = 0; ks < 4; ++ks) {
            bf16x8 w0 = *(const bf16x8*)(qkvw + (2 * DIM + h * 32 +  0 + c) * DIM + ks * 32 + g * 8);
            bf16x8 w1 = *(const bf16x8*)(qkvw + (2 * DIM + h * 32 + 16 + c) * DIM + ks * 32 + g * 8);
            #pragma unroll
            for (int mt = 0; mt < 4; ++mt) {
                bf16x8 a = LDX(mt, ks);
                acc[mt][0] = MFMA32(a, w0, acc[mt][0]);
                acc[mt][1] = MFMA32(a, w1, acc[mt][1]);
            }
        }
        #pragma unroll
        for (int mt = 0; mt < 4; ++mt)
            #pragma unroll
            for (int nt = 0; nt < 2; ++nt) vp[mt][nt] = pk4(acc[mt][nt]);
    }

    // ---- fused per-ntq: S^T tile -> softmax -> PV -> stream O to ao LDS ----
    {
        const float* cw = cmb + (size_t)((b % nw) * NH + h) * 4096;
        #pragma unroll
        for (int ntq = 0; ntq < 4; ++ntq) {
            f32x4 s[4];
            #pragma unroll
            for (int mtk = 0; mtk < 4; ++mtk)
                s[mtk] = *(const f32x4*)(cw + (ntq * 16 + c) * 64 + mtk * 16 + g * 4);
            #pragma unroll
            for (int mtk = 0; mtk < 4; ++mtk) {
                s[mtk] = MFMA16(asi(kp[0][mtk]), asi(qp[0][ntq]), s[mtk]);
                s[mtk] = MFMA16(asi(kp[1][mtk]), asi(qp[1][ntq]), s[mtk]);
            }
            float m = s[0][0];
            #pragma unroll
            for (int mtk = 0; mtk < 4; ++mtk)
                #pragma unroll
                for (int r = 0; r < 4; ++r) m = fmaxf(m, s[mtk][r]);
            m = fmaxf(m, __shfl_xor(m, 16));
            m = fmaxf(m, __shfl_xor(m, 32));
            float sum = 0.f;
            #pragma unroll
            for (int mtk = 0; mtk < 4; ++mtk)
                #pragma unroll
                for (int r = 0; r < 4; ++r) {
                    float p = __expf(s[mtk][r] - m);
                    s[mtk][r] = p;
                    sum += p;
                }
            sum += __shfl_xor(sum, 16);
            sum += __shfl_xor(sum, 32);
            const float dinv = 1.f / sum;

            bf16x4 pa[4];
            #pragma unroll
            for (int mtk = 0; mtk < 4; ++mtk) pa[mtk] = pk4(s[mtk]);

            f32x4 o0 = {0.f, 0.f, 0.f, 0.f}, o1 = {0.f, 0.f, 0.f, 0.f};
            #pragma unroll
            for (int mtk = 0; mtk < 4; ++mtk) {
                o0 = MFMA16(asi(vp[mtk][0]), asi(pa[mtk]), o0);
                o1 = MFMA16(asi(vp[mtk][1]), asi(pa[mtk]), o1);
            }
            f32x4 so0 = { o0[0]*dinv, o0[1]*dinv, o0[2]*dinv, o0[3]*dinv };
            f32x4 so1 = { o1[0]*dinv, o1[1]*dinv, o1[2]*dinv, o1[3]*dinv };
            // ao[tok][d] bf16, 16B-granule swizzle ^ (c&15); mtd = 0 and 1
            const int base = (ntq*16 + c)*256 + ((g&1) << 3);
            *(bf16x4*)(aosm + base + ((((h*4 + 0 + (g>>1)) ^ c) & 15) << 4)) = pk4(so0);
            *(bf16x4*)(aosm + base + ((((h*4 + 2 + (g>>1)) ^ c) & 15) << 4)) = pk4(so1);
        }
    }
    __syncthreads();   // ao writes complete (x region untouched; no overlay)

    // ---- out^T = Wp . ao^T : wave owns 32 output cols; f32x4 stores ----
    {
        f32x4 po[2][4];
        #pragma unroll
        for (int mtO = 0; mtO < 2; ++mtO) {
            const f32x4 pb4 = *(const f32x4*)(proj_b + wave * 32 + mtO * 16 + g * 4);
            #pragma unroll
            for (int nt = 0; nt < 4; ++nt) po[mtO][nt] = pb4;
        }
        #pragma unroll
        for (int ks = 0; ks < 4; ++ks) {
            bf16x8 w0 = *(const bf16x8*)(projw + (wave * 32 +  0 + c) * DIM + ks * 32 + g * 8);
            bf16x8 w1 = *(const bf16x8*)(projw + (wave * 32 + 16 + c) * DIM + ks * 32 + g * 8);
            bf16x8 aof[4];
            #pragma unroll
            for (int nt = 0; nt < 4; ++nt)
                aof[nt] = *(const bf16x8*)(aosm + (nt*16 + c)*256 + ((((ks*4 + g) ^ c) & 15) << 4));
            #pragma unroll
            for (int nt = 0; nt < 4; ++nt) {
                po[0][nt] = MFMA32(w0, aof[nt], po[0][nt]);
                po[1][nt] = MFMA32(w1, aof[nt], po[1][nt]);
            }
        }
        float* og = out + (size_t)b * (NTOK * DIM);
        #pragma unroll
        for (int nt = 0; nt < 4; ++nt) {
            const int tok = nt * 16 + c;
            if (tok < NTOK) {
                #pragma unroll
                for (int mtO = 0; mtO < 2; ++mtO)
                    *(f32x4*)(og + tok * DIM + wave * 32 + mtO * 16 + g * 4) = po[mtO][nt];
            }
        }
    }
    #undef LDX
}

extern "C" void kernel_launch(void* const* d_in, const int* in_sizes, int n_in,
                              void* d_out, int out_size, void* d_ws, size_t ws_size,
                              hipStream_t stream) {
    (void)n_in; (void)out_size; (void)ws_size;
    const float* x          = (const float*)d_in[0];
    const float* mask       = (const float*)d_in[1];
    const float* qkv_w      = (const float*)d_in[2];
    const float* qkv_b      = (const float*)d_in[3];
    const float* proj_w     = (const float*)d_in[4];
    const float* proj_b     = (const float*)d_in[5];
    const float* bias_table = (const float*)d_in[6];
    const int*   rel_index  = (const int*)d_in[7];
    float* out = (float*)d_out;

    char* ws = (char*)d_ws;
    bfloat_t* qkvw_b  = (bfloat_t*)ws;              // 98304 B
    bfloat_t* projw_b = (bfloat_t*)(ws + 98304);    // 32768 B
    float*    cmb     = (float*)(ws + 131072);      // nw*NH*64*64*4 B

    const int B  = in_sizes[0] / (NTOK * DIM);
    const int nw = in_sizes[1] / (NTOK * NTOK);

    prep_weights<<<dim3((QKVN * DIM + 255) / 256), dim3(256), 0, stream>>>(qkv_w, proj_w, qkvw_b, projw_b);
    prep_cmb<<<dim3(nw * NH), dim3(256), 0, stream>>>(mask, bias_table, rel_index, cmb);
    win_attn<<<dim3(B), dim3(256), 0, stream>>>(x, qkv_b, proj_b, qkvw_b, projw_b, cmb, out, nw);
}